// Round 6
// baseline (434.716 us; speedup 1.0000x reference)
//
#include <hip/hip_runtime.h>
#include <math.h>

#define B_ 4
#define C_ 512
#define T_ 8
#define L_ 512
#define H_ 8
#define HD_ 64

typedef unsigned short ushort_t;
using short8 = __attribute__((ext_vector_type(8))) short;
using f4 = __attribute__((ext_vector_type(4))) float;

#define GLOAD_LDS(gp, lp)                                                      \
  __builtin_amdgcn_global_load_lds(                                            \
      (const __attribute__((address_space(1))) unsigned int*)(gp),             \
      (__attribute__((address_space(3))) unsigned int*)(lp), 16, 0, 0)

// RNE float->bf16 pack (a -> low 16, b -> high 16). Finite inputs only.
__device__ __forceinline__ unsigned pack_bf16(float a, float b) {
  union { float f; unsigned u; } ua, ub;
  ua.f = a; ub.f = b;
  unsigned ra = (ua.u + 0x7FFFu + ((ua.u >> 16) & 1u)) >> 16;
  unsigned rb = (ub.u + 0x7FFFu + ((ub.u >> 16) & 1u)) >> 16;
  return (rb << 16) | (ra & 0xFFFFu);
}
__device__ __forceinline__ ushort_t bf16_1(float a) {
  union { float f; unsigned u; } ua; ua.f = a;
  return (ushort_t)((ua.u + 0x7FFFu + ((ua.u >> 16) & 1u)) >> 16);
}

// ---------------------------------------------------------------------------
// Workspace: pooled 16384 | gwp 256 | h1 16384 | bf16 buffers:
//   ebfT,xbfT,Qbf,Kbf,Vbf,obfT 6x4194304 fl | Wqb 131072 | Wkvb 262144 | Wmb 131072
// Layouts: ebfT/xbfT/obfT = [bt][l][c] bf16 ; Qbf/Kbf = [bt][h][l][d]
//          (pre-normalized; Q also *0.125) ; Vbf = [bt][h][d][l] (*gw)
// ---------------------------------------------------------------------------

// h1[bt][row] = tanh(dot(Wg1[row], pooled[bt]) + bg1[row]); one wave per row.
__global__ __launch_bounds__(256) void gate1_kernel(const float* __restrict__ pooled,
                                                    const float* __restrict__ Wg1,
                                                    const float* __restrict__ bg1,
                                                    float* __restrict__ h1) {
  int w = threadIdx.x >> 6, lane = threadIdx.x & 63;
  int row = blockIdx.x * 4 + w;
  int bt = blockIdx.y;
  const float* wr = Wg1 + (size_t)row * C_;
  const float* pr = pooled + bt * C_;
  float s = 0.f;
#pragma unroll
  for (int i = 0; i < 8; ++i) s += wr[lane + i * 64] * pr[lane + i * 64];
#pragma unroll
  for (int off = 32; off > 0; off >>= 1) s += __shfl_down(s, off, 64);
  if (lane == 0) h1[bt * C_ + row] = tanhf(s + bg1[row]);
}

__global__ __launch_bounds__(256) void gate2_kernel(const float* __restrict__ h1,
                                                    const float* __restrict__ Wg2,
                                                    const float* __restrict__ bg2,
                                                    float* __restrict__ gwp) {
  __shared__ float part[256];
  __shared__ float gl[H_];
  int bt = blockIdx.x, tid = threadIdx.x;
  int h = tid >> 5, s = tid & 31;
  const float* w2 = Wg2 + (size_t)h * C_;
  const float* hb = h1 + bt * C_;
  float p = 0.f;
  for (int c = s; c < C_; c += 32) p += w2[c] * hb[c];
  part[tid] = p;
  __syncthreads();
  if (tid < H_) {
    float a = bg2[tid];
    for (int i = 0; i < 32; ++i) a += part[tid * 32 + i];
    gl[tid] = a;
  }
  __syncthreads();
  if (tid == 0) {
    float m = -1e30f;
    for (int i = 0; i < H_; ++i) m = fmaxf(m, gl[i]);
    float sum = 0.f;
    float ex[H_];
    for (int i = 0; i < H_; ++i) { ex[i] = expf(gl[i] - m); sum += ex[i]; }
    for (int i = 0; i < H_; ++i) gwp[bt * H_ + i] = ex[i] / sum;
  }
}

// fp32 -> bf16 for all three weight matrices in one launch.
// total elements = 262144 (Wq) + 524288 (Wkv) + 262144 (Wm) = 1048576.
__global__ __launch_bounds__(256) void cvt3_kernel(const float* __restrict__ Wq,
                                                   const float* __restrict__ Wkv,
                                                   const float* __restrict__ Wm,
                                                   ushort_t* __restrict__ dWq,
                                                   ushort_t* __restrict__ dWkv,
                                                   ushort_t* __restrict__ dWm) {
  int i = (blockIdx.x * 256 + threadIdx.x) * 8;
  const float* s;
  ushort_t* d;
  int off;
  if (i < 262144)      { s = Wq;  d = dWq;  off = i; }
  else if (i < 786432) { s = Wkv; d = dWkv; off = i - 262144; }
  else                 { s = Wm;  d = dWm;  off = i - 786432; }
  float4 a = *(const float4*)(s + off);
  float4 b = *(const float4*)(s + off + 4);
  uint4 o;
  o.x = pack_bf16(a.x, a.y); o.y = pack_bf16(a.z, a.w);
  o.z = pack_bf16(b.x, b.y); o.w = pack_bf16(b.z, b.w);
  *(uint4*)(d + off) = o;
}

// Transpose-convert both e and x in one launch: grid z 0..63.
// z<32: src=e -> ebfT (+ pooled atomics); z>=32: src=x -> xbfT.
__global__ __launch_bounds__(256) void tconv_kernel(const float* __restrict__ e,
                                                    const float* __restrict__ x,
                                                    ushort_t* __restrict__ ebfT,
                                                    ushort_t* __restrict__ xbfT,
                                                    float* __restrict__ pooled) {
  __shared__ float tb[64][65];
  int tid = threadIdx.x;
  bool isE = blockIdx.z < 32;
  int bt = isE ? blockIdx.z : blockIdx.z - 32;
  const float* src = isE ? e : x;
  ushort_t* dst = isE ? ebfT : xbfT;
  int b = bt >> 3, t = bt & 7;
  int c0 = blockIdx.y * 64, l0 = blockIdx.x * 64;
  const float* sp = src + (((size_t)(b * C_ + c0) * T_) + t) * L_ + l0;
  int j = tid & 63, i0 = tid >> 6;
#pragma unroll
  for (int p = 0; p < 16; ++p) {
    int i = p * 4 + i0;
    tb[i][j] = sp[(size_t)i * (T_ * L_) + j];
  }
  __syncthreads();
  if (isE) {
    int c = tid >> 2, part = tid & 3;
    float s = 0.f;
#pragma unroll
    for (int k = 0; k < 16; ++k) s += tb[c][part * 16 + k];
    s += __shfl_down(s, 1);
    s += __shfl_down(s, 2);
    if (part == 0) atomicAdd(&pooled[bt * C_ + c0 + c], s * (1.0f / L_));
  }
  int ii = (tid & 31) * 2, jj0 = tid >> 5;
  ushort_t* dp = dst + ((size_t)bt * L_ + l0) * C_ + c0;
#pragma unroll
  for (int p = 0; p < 8; ++p) {
    int jj = p * 8 + jj0;
    *(unsigned*)(dp + (size_t)jj * C_ + ii) = pack_bf16(tb[ii][jj], tb[ii + 1][jj]);
  }
}

// ---------------------------------------------------------------------------
// bf16 MFMA GEMM: C[m][n] = A[m][k] . BT[n][k], K=512, 128x128 tile, BK=32.
// mode 0: Out fp32 (B,C,T,L) = C + bias[m] + resid   (A/BT/bias args, grid y=4)
// mode 3: fused qkv. grid y in [0,12): y<4 -> q (normalize * 0.125 -> Qdst);
//   y>=4 -> kv; m<512: k normalize -> Kdst; m>=512: v normalize*gw -> Vdst.
// ---------------------------------------------------------------------------
__global__ __launch_bounds__(256, 2) void gemm_mfma(
    const ushort_t* __restrict__ Aq, const ushort_t* __restrict__ BTq,
    const float* __restrict__ biasq, const ushort_t* __restrict__ Akv,
    const ushort_t* __restrict__ BTkv, const float* __restrict__ biaskv,
    int mode, float* __restrict__ Out, const float* __restrict__ resid,
    ushort_t* __restrict__ Qdst, ushort_t* __restrict__ Kdst,
    ushort_t* __restrict__ Vdst, const float* __restrict__ gwp) {
  __shared__ alignas(16) ushort_t As[128 * 32];
  __shared__ alignas(16) ushort_t Bs[128 * 32];
  int tid = threadIdx.x;
  int w = tid >> 6, lane = tid & 63, l15 = lane & 15, q = lane >> 4;
  int n0 = blockIdx.x * 128, bt = blockIdx.z;
  int wm = (w >> 1) * 64, wn = (w & 1) * 64;

  const ushort_t* A;
  const ushort_t* BT;
  const float* bias;
  int m0, lmode;
  if (mode == 3) {
    if (blockIdx.y < 4) {
      A = Aq; BT = BTq; bias = biasq; lmode = 1; m0 = blockIdx.y * 128;
    } else {
      A = Akv; BT = BTkv; bias = biaskv; lmode = 2; m0 = (blockIdx.y - 4) * 128;
    }
  } else {
    A = Aq; BT = BTq; bias = biasq; lmode = 0; m0 = blockIdx.y * 128;
  }
  const ushort_t* Bbt = BT + (size_t)bt * C_ * C_;

  int c0 = w * 64 + lane, c1 = 256 + w * 64 + lane;
  const ushort_t* ag0 = A + (size_t)(m0 + (c0 >> 2)) * 512 + (c0 & 3) * 8;
  const ushort_t* ag1 = A + (size_t)(m0 + (c1 >> 2)) * 512 + (c1 & 3) * 8;
  const ushort_t* bg0 = Bbt + (size_t)(n0 + (c0 >> 2)) * 512 + (c0 & 3) * 8;
  const ushort_t* bg1 = Bbt + (size_t)(n0 + (c1 >> 2)) * 512 + (c1 & 3) * 8;
  ushort_t* la0 = As + (size_t)(w * 64) * 8;
  ushort_t* la1 = As + (size_t)(256 + w * 64) * 8;
  ushort_t* lb0 = Bs + (size_t)(w * 64) * 8;
  ushort_t* lb1 = Bs + (size_t)(256 + w * 64) * 8;

  f4 acc[4][4];
#pragma unroll
  for (int i = 0; i < 4; ++i)
#pragma unroll
    for (int j = 0; j < 4; ++j) acc[i][j] = (f4){0.f, 0.f, 0.f, 0.f};

  for (int k0 = 0; k0 < 512; k0 += 32) {
    __syncthreads();
    GLOAD_LDS(ag0 + k0, la0);
    GLOAD_LDS(ag1 + k0, la1);
    GLOAD_LDS(bg0 + k0, lb0);
    GLOAD_LDS(bg1 + k0, lb1);
    __syncthreads();
    short8 af[4], bf[4];
#pragma unroll
    for (int mt = 0; mt < 4; ++mt)
      af[mt] = *(const short8*)&As[(size_t)(wm + mt * 16 + l15) * 32 + q * 8];
#pragma unroll
    for (int nt = 0; nt < 4; ++nt)
      bf[nt] = *(const short8*)&Bs[(size_t)(wn + nt * 16 + l15) * 32 + q * 8];
#pragma unroll
    for (int mt = 0; mt < 4; ++mt)
#pragma unroll
      for (int nt = 0; nt < 4; ++nt)
        acc[mt][nt] =
            __builtin_amdgcn_mfma_f32_16x16x32_bf16(af[mt], bf[nt], acc[mt][nt], 0, 0, 0);
  }

#pragma unroll
  for (int mt = 0; mt < 4; ++mt)
#pragma unroll
    for (int r = 0; r < 4; ++r) {
      float bb = bias[m0 + wm + mt * 16 + q * 4 + r];
#pragma unroll
      for (int nt = 0; nt < 4; ++nt) acc[mt][nt][r] += bb;
    }

  if (lmode == 0) {
    int b = bt >> 3, t = bt & 7;
    float* Ob = Out + (size_t)b * (C_ * T_ * L_) + (size_t)t * L_;
    const float* Rb = resid + (size_t)b * (C_ * T_ * L_) + (size_t)t * L_;
#pragma unroll
    for (int mt = 0; mt < 4; ++mt)
#pragma unroll
      for (int r = 0; r < 4; ++r) {
        size_t ro = (size_t)(m0 + wm + mt * 16 + q * 4 + r) * (T_ * L_);
#pragma unroll
        for (int nt = 0; nt < 4; ++nt) {
          int n = n0 + wn + nt * 16 + l15;
          Ob[ro + n] = acc[mt][nt][r] + Rb[ro + n];
        }
      }
    return;
  }

  // normalization over the wave's 64 m-rows (= one full head) per column
  float scale[4];
#pragma unroll
  for (int nt = 0; nt < 4; ++nt) {
    float s = 0.f;
#pragma unroll
    for (int mt = 0; mt < 4; ++mt)
#pragma unroll
      for (int r = 0; r < 4; ++r) s += acc[mt][nt][r] * acc[mt][nt][r];
    s += __shfl_xor(s, 16);
    s += __shfl_xor(s, 32);
    scale[nt] = s;
  }
  int hh = ((m0 + wm) >> 6) & 7;
  bool isv = (lmode == 2) && (m0 + wm >= 512);
  float mult = isv ? gwp[bt * H_ + hh] : (lmode == 1 ? 0.125f : 1.0f);
#pragma unroll
  for (int nt = 0; nt < 4; ++nt)
    scale[nt] = mult / fmaxf(sqrtf(scale[nt]), 1e-12f);

  if (!isv) {
    ushort_t* Db = (lmode == 1 ? Qdst : Kdst) + (size_t)(bt * H_ + hh) * 512 * 64;
#pragma unroll
    for (int nt = 0; nt < 4; ++nt) {
      int l = n0 + wn + nt * 16 + l15;
      ushort_t* rowp = Db + (size_t)l * 64;
#pragma unroll
      for (int mt = 0; mt < 4; ++mt) {
        uint2 pk;
        pk.x = pack_bf16(acc[mt][nt][0] * scale[nt], acc[mt][nt][1] * scale[nt]);
        pk.y = pack_bf16(acc[mt][nt][2] * scale[nt], acc[mt][nt][3] * scale[nt]);
        *(uint2*)&rowp[mt * 16 + q * 4] = pk;
      }
    }
  } else {
    ushort_t* Vb = Vdst + (size_t)(bt * H_ + hh) * 64 * 512;
#pragma unroll
    for (int mt = 0; mt < 4; ++mt)
#pragma unroll
      for (int r = 0; r < 4; ++r) {
        int d = mt * 16 + q * 4 + r;
        ushort_t* rp = Vb + (size_t)d * 512 + n0 + wn;
#pragma unroll
        for (int nt = 0; nt < 4; ++nt)
          rp[nt * 16 + l15] = bf16_1(acc[mt][nt][r] * scale[nt]);
      }
  }
}

// Flash MFMA attention, one block per (h,bt): 512 threads = 8 waves, 64
// queries per wave (4 x 16-i frags). No LDS/barriers; K double-buffered in
// registers (prefetch tile j+1 during tile j), V issued at tile top BEFORE
// the K prefetch so vmcnt-FIFO waits on V don't drain the K prefetch.
// No-max softmax is exact: q,k unit vectors => |s| <= 0.125.
__global__ __launch_bounds__(512, 2) void attn_kernel(
    const ushort_t* __restrict__ Qbf, const ushort_t* __restrict__ Kbf,
    const ushort_t* __restrict__ Vbf, const float* __restrict__ gwp,
    ushort_t* __restrict__ obfT) {
  int tid = threadIdx.x;
  int w = tid >> 6, lane = tid & 63, l15 = lane & 15, q = lane >> 4;
  int h = blockIdx.x, bt = blockIdx.y;

  const ushort_t* Qg = Qbf + (size_t)(bt * H_ + h) * 512 * 64;
  const ushort_t* Kg = Kbf + (size_t)(bt * H_ + h) * 512 * 64;
  const ushort_t* Vg = Vbf + (size_t)(bt * H_ + h) * 64 * 512;

  short8 qf[4][2];
#pragma unroll
  for (int f = 0; f < 4; ++f) {
    const ushort_t* qrow = Qg + (size_t)(w * 64 + f * 16 + l15) * 64;
    qf[f][0] = *(const short8*)&qrow[q * 8];
    qf[f][1] = *(const short8*)&qrow[32 + q * 8];
  }

  f4 acc[4][4];
#pragma unroll
  for (int f = 0; f < 4; ++f)
#pragma unroll
    for (int dt = 0; dt < 4; ++dt) acc[f][dt] = (f4){0.f, 0.f, 0.f, 0.f};
  float lsum[4] = {0.f, 0.f, 0.f, 0.f};
  bool hi_half = (lane >= 32);
  int qh2 = (q & 1) * 2;

  // prologue: K frags for tile 0
  short8 kf[2][4][2];
#pragma unroll
  for (int jt = 0; jt < 4; ++jt) {
    const ushort_t* kr = Kg + (size_t)(jt * 16 + l15) * 64;
    kf[0][jt][0] = *(const short8*)&kr[q * 8];
    kf[0][jt][1] = *(const short8*)&kr[32 + q * 8];
  }

#pragma unroll
  for (int jj = 0; jj < 8; ++jj) {
    const int j0 = jj * 64;
    const int cur = jj & 1;
    // current-tile V loads (issued FIRST -> waiting on them leaves next-K in flight)
    short8 vf[2][4];
#pragma unroll
    for (int ks2 = 0; ks2 < 2; ++ks2)
#pragma unroll
      for (int dt = 0; dt < 4; ++dt)
        vf[ks2][dt] = *(const short8*)(Vg + (size_t)(dt * 16 + l15) * 512 + j0 +
                                       ks2 * 32 + q * 8);
    // prefetch next tile's K
    if (jj < 7) {
#pragma unroll
      for (int jt = 0; jt < 4; ++jt) {
        const ushort_t* kr = Kg + (size_t)(j0 + 64 + jt * 16 + l15) * 64;
        kf[cur ^ 1][jt][0] = *(const short8*)&kr[q * 8];
        kf[cur ^ 1][jt][1] = *(const short8*)&kr[32 + q * 8];
      }
    }

#pragma unroll
    for (int f = 0; f < 4; ++f) {
      // S^T tiles (16j x 16i), C-layout: col=i(l15), row=j(q*4+r)
      f4 sc[4];
#pragma unroll
      for (int jt = 0; jt < 4; ++jt) {
        f4 c = {0.f, 0.f, 0.f, 0.f};
        c = __builtin_amdgcn_mfma_f32_16x16x32_bf16(kf[cur][jt][0], qf[f][0], c, 0, 0, 0);
        c = __builtin_amdgcn_mfma_f32_16x16x32_bf16(kf[cur][jt][1], qf[f][1], c, 0, 0, 0);
        sc[jt] = c;
      }
      float ls = 0.f;
#pragma unroll
      for (int jt = 0; jt < 4; ++jt)
#pragma unroll
        for (int r = 0; r < 4; ++r) {
          float p = __expf(sc[jt][r]);
          sc[jt][r] = p;
          ls += p;
        }
      lsum[f] += ls;

      unsigned pk01[4], pk23[4];
#pragma unroll
      for (int jt = 0; jt < 4; ++jt) {
        pk01[jt] = pack_bf16(sc[jt][0], sc[jt][1]);
        pk23[jt] = pack_bf16(sc[jt][2], sc[jt][3]);
      }
      // PV: O^T += V^T . P^T  (P^T shuffled into B-operand layout)
#pragma unroll
      for (int ks2 = 0; ks2 < 2; ++ks2) {
        union { unsigned u[4]; short8 s; } bu;
#pragma unroll
        for (int r = 0; r < 4; ++r) {
          int src = (qh2 + (r >> 1)) * 16 + l15;
          unsigned pl = (r & 1) ? pk23[ks2 * 2] : pk01[ks2 * 2];
          unsigned ph = (r & 1) ? pk23[ks2 * 2 + 1] : pk01[ks2 * 2 + 1];
          unsigned lo = __shfl(pl, src);
          unsigned hi = __shfl(ph, src);
          bu.u[r] = hi_half ? hi : lo;
        }
#pragma unroll
        for (int dt = 0; dt < 4; ++dt)
          acc[f][dt] = __builtin_amdgcn_mfma_f32_16x16x32_bf16(vf[ks2][dt], bu.s,
                                                               acc[f][dt], 0, 0, 0);
      }
    }
  }

  // epilogue: reduce l-sums, *gw, store bf16 to obfT[l][c]
  float g = gwp[bt * H_ + h];
#pragma unroll
  for (int f = 0; f < 4; ++f) {
    float ls = lsum[f];
    ls += __shfl_xor(ls, 16);
    ls += __shfl_xor(ls, 32);
    float inv = g / ls;
    int iglob = w * 64 + f * 16 + l15;
    ushort_t* ob = obfT + ((size_t)(bt * 512 + iglob)) * 512 + h * 64;
#pragma unroll
    for (int dt = 0; dt < 4; ++dt) {
      uint2 pk;
      pk.x = pack_bf16(acc[f][dt][0] * inv, acc[f][dt][1] * inv);
      pk.y = pack_bf16(acc[f][dt][2] * inv, acc[f][dt][3] * inv);
      *(uint2*)&ob[dt * 16 + q * 4] = pk;
    }
  }
}

extern "C" void kernel_launch(void* const* d_in, const int* in_sizes, int n_in,
                              void* d_out, int out_size, void* d_ws, size_t ws_size,
                              hipStream_t stream) {
  const float* e   = (const float*)d_in[0];
  const float* x   = (const float*)d_in[1];
  const float* Wq  = (const float*)d_in[2];
  const float* bq  = (const float*)d_in[3];
  const float* Wkv = (const float*)d_in[4];
  const float* bkv = (const float*)d_in[5];
  const float* Wm  = (const float*)d_in[6];
  const float* bm  = (const float*)d_in[7];
  const float* Wg1 = (const float*)d_in[8];
  const float* bg1 = (const float*)d_in[9];
  const float* Wg2 = (const float*)d_in[10];
  const float* bg2 = (const float*)d_in[11];
  float* out = (float*)d_out;

  float* ws = (float*)d_ws;
  float* pooled = ws;                  // 16384
  float* gwp    = ws + 16384;          // 256
  float* h1buf  = ws + 16640;          // 16384
  float* fb     = ws + 33024;
  ushort_t* ebfT = (ushort_t*)(fb);
  ushort_t* xbfT = (ushort_t*)(fb + 1 * 4194304);
  ushort_t* Qbf  = (ushort_t*)(fb + 2 * 4194304);
  ushort_t* Kbf  = (ushort_t*)(fb + 3 * 4194304);
  ushort_t* Vbf  = (ushort_t*)(fb + 4 * 4194304);
  ushort_t* obfT = (ushort_t*)(fb + 5 * 4194304);
  ushort_t* Wqb  = (ushort_t*)(fb + 6 * 4194304);
  ushort_t* Wkvb = Wqb + 262144;
  ushort_t* Wmb  = Wkvb + 524288;

  hipMemsetAsync(pooled, 0, 16384 * sizeof(float), stream);
  cvt3_kernel<<<dim3(512), dim3(256), 0, stream>>>(Wq, Wkv, Wm, Wqb, Wkvb, Wmb);
  tconv_kernel<<<dim3(8, 8, 64), dim3(256), 0, stream>>>(e, x, ebfT, xbfT, pooled);
  gate1_kernel<<<dim3(128, 32), dim3(256), 0, stream>>>(pooled, Wg1, bg1, h1buf);
  gate2_kernel<<<dim3(32), dim3(256), 0, stream>>>(h1buf, Wg2, bg2, gwp);
  // fused q + kv projections (normalize epilogues) -> Qbf, Kbf, Vbf
  gemm_mfma<<<dim3(4, 12, 32), dim3(256), 0, stream>>>(
      Wqb, ebfT, bq, Wkvb, xbfT, bkv, 3, nullptr, nullptr, Qbf, Kbf, Vbf, gwp);
  // attention -> obfT (one block per (h,bt), K reg-double-buffered)
  attn_kernel<<<dim3(H_, 32), dim3(512), 0, stream>>>(Qbf, Kbf, Vbf, gwp, obfT);
  // output projection + bias + residual -> out
  gemm_mfma<<<dim3(4, 4, 32), dim3(256), 0, stream>>>(
      Wmb, obfT, bm, nullptr, nullptr, nullptr, 0, out, x, nullptr, nullptr,
      nullptr, gwp);
}

// Round 7
// 271.134 us; speedup vs baseline: 1.6033x; 1.6033x over previous
//
#include <hip/hip_runtime.h>
#include <math.h>

#define B_ 4
#define C_ 512
#define T_ 8
#define L_ 512
#define H_ 8
#define HD_ 64

typedef unsigned short ushort_t;
using short8 = __attribute__((ext_vector_type(8))) short;
using f4 = __attribute__((ext_vector_type(4))) float;

#define GLOAD_LDS(gp, lp)                                                      \
  __builtin_amdgcn_global_load_lds(                                            \
      (const __attribute__((address_space(1))) unsigned int*)(gp),             \
      (__attribute__((address_space(3))) unsigned int*)(lp), 16, 0, 0)

// RNE float->bf16 pack (a -> low 16, b -> high 16). Finite inputs only.
__device__ __forceinline__ unsigned pack_bf16(float a, float b) {
  union { float f; unsigned u; } ua, ub;
  ua.f = a; ub.f = b;
  unsigned ra = (ua.u + 0x7FFFu + ((ua.u >> 16) & 1u)) >> 16;
  unsigned rb = (ub.u + 0x7FFFu + ((ub.u >> 16) & 1u)) >> 16;
  return (rb << 16) | (ra & 0xFFFFu);
}
__device__ __forceinline__ ushort_t bf16_1(float a) {
  union { float f; unsigned u; } ua; ua.f = a;
  return (ushort_t)((ua.u + 0x7FFFu + ((ua.u >> 16) & 1u)) >> 16);
}

// ---------------------------------------------------------------------------
// Workspace: pooled 16384 | gwp 256 | h1 16384 | bf16 buffers:
//   ebfT,xbfT,Qbf,Kbf,Vbf,obfT 6x4194304 fl | Wqb 131072 | Wkvb 262144 | Wmb 131072
// Layouts: ebfT/xbfT/obfT = [bt][l][c] bf16 ; Qbf/Kbf = [bt][h][l][d]
//          (pre-normalized; Q also *0.125) ; Vbf = [bt][h][d][l] (*gw)
// ---------------------------------------------------------------------------

// h1[bt][row] = tanh(dot(Wg1[row], pooled[bt]) + bg1[row]); one wave per row.
__global__ __launch_bounds__(256) void gate1_kernel(const float* __restrict__ pooled,
                                                    const float* __restrict__ Wg1,
                                                    const float* __restrict__ bg1,
                                                    float* __restrict__ h1) {
  int w = threadIdx.x >> 6, lane = threadIdx.x & 63;
  int row = blockIdx.x * 4 + w;
  int bt = blockIdx.y;
  const float* wr = Wg1 + (size_t)row * C_;
  const float* pr = pooled + bt * C_;
  float s = 0.f;
#pragma unroll
  for (int i = 0; i < 8; ++i) s += wr[lane + i * 64] * pr[lane + i * 64];
#pragma unroll
  for (int off = 32; off > 0; off >>= 1) s += __shfl_down(s, off, 64);
  if (lane == 0) h1[bt * C_ + row] = tanhf(s + bg1[row]);
}

__global__ __launch_bounds__(256) void gate2_kernel(const float* __restrict__ h1,
                                                    const float* __restrict__ Wg2,
                                                    const float* __restrict__ bg2,
                                                    float* __restrict__ gwp) {
  __shared__ float part[256];
  __shared__ float gl[H_];
  int bt = blockIdx.x, tid = threadIdx.x;
  int h = tid >> 5, s = tid & 31;
  const float* w2 = Wg2 + (size_t)h * C_;
  const float* hb = h1 + bt * C_;
  float p = 0.f;
  for (int c = s; c < C_; c += 32) p += w2[c] * hb[c];
  part[tid] = p;
  __syncthreads();
  if (tid < H_) {
    float a = bg2[tid];
    for (int i = 0; i < 32; ++i) a += part[tid * 32 + i];
    gl[tid] = a;
  }
  __syncthreads();
  if (tid == 0) {
    float m = -1e30f;
    for (int i = 0; i < H_; ++i) m = fmaxf(m, gl[i]);
    float sum = 0.f;
    float ex[H_];
    for (int i = 0; i < H_; ++i) { ex[i] = expf(gl[i] - m); sum += ex[i]; }
    for (int i = 0; i < H_; ++i) gwp[bt * H_ + i] = ex[i] / sum;
  }
}

// fp32 -> bf16 for all three weight matrices in one launch.
__global__ __launch_bounds__(256) void cvt3_kernel(const float* __restrict__ Wq,
                                                   const float* __restrict__ Wkv,
                                                   const float* __restrict__ Wm,
                                                   ushort_t* __restrict__ dWq,
                                                   ushort_t* __restrict__ dWkv,
                                                   ushort_t* __restrict__ dWm) {
  int i = (blockIdx.x * 256 + threadIdx.x) * 8;
  const float* s;
  ushort_t* d;
  int off;
  if (i < 262144)      { s = Wq;  d = dWq;  off = i; }
  else if (i < 786432) { s = Wkv; d = dWkv; off = i - 262144; }
  else                 { s = Wm;  d = dWm;  off = i - 786432; }
  float4 a = *(const float4*)(s + off);
  float4 b = *(const float4*)(s + off + 4);
  uint4 o;
  o.x = pack_bf16(a.x, a.y); o.y = pack_bf16(a.z, a.w);
  o.z = pack_bf16(b.x, b.y); o.w = pack_bf16(b.z, b.w);
  *(uint4*)(d + off) = o;
}

// Transpose-convert both e and x in one launch: grid z 0..63.
// z<32: src=e -> ebfT (+ pooled atomics); z>=32: src=x -> xbfT.
__global__ __launch_bounds__(256) void tconv_kernel(const float* __restrict__ e,
                                                    const float* __restrict__ x,
                                                    ushort_t* __restrict__ ebfT,
                                                    ushort_t* __restrict__ xbfT,
                                                    float* __restrict__ pooled) {
  __shared__ float tb[64][65];
  int tid = threadIdx.x;
  bool isE = blockIdx.z < 32;
  int bt = isE ? blockIdx.z : blockIdx.z - 32;
  const float* src = isE ? e : x;
  ushort_t* dst = isE ? ebfT : xbfT;
  int b = bt >> 3, t = bt & 7;
  int c0 = blockIdx.y * 64, l0 = blockIdx.x * 64;
  const float* sp = src + (((size_t)(b * C_ + c0) * T_) + t) * L_ + l0;
  int j = tid & 63, i0 = tid >> 6;
#pragma unroll
  for (int p = 0; p < 16; ++p) {
    int i = p * 4 + i0;
    tb[i][j] = sp[(size_t)i * (T_ * L_) + j];
  }
  __syncthreads();
  if (isE) {
    int c = tid >> 2, part = tid & 3;
    float s = 0.f;
#pragma unroll
    for (int k = 0; k < 16; ++k) s += tb[c][part * 16 + k];
    s += __shfl_down(s, 1);
    s += __shfl_down(s, 2);
    if (part == 0) atomicAdd(&pooled[bt * C_ + c0 + c], s * (1.0f / L_));
  }
  int ii = (tid & 31) * 2, jj0 = tid >> 5;
  ushort_t* dp = dst + ((size_t)bt * L_ + l0) * C_ + c0;
#pragma unroll
  for (int p = 0; p < 8; ++p) {
    int jj = p * 8 + jj0;
    *(unsigned*)(dp + (size_t)jj * C_ + ii) = pack_bf16(tb[ii][jj], tb[ii + 1][jj]);
  }
}

// ---------------------------------------------------------------------------
// bf16 MFMA GEMM: C[m][n] = A[m][k] . BT[n][k], K=512, 128x128 tile, BK=32.
// mode 0: Out fp32 (B,C,T,L) = C + bias[m] + resid   (A/BT/bias args, grid y=4)
// mode 3: fused qkv. grid y in [0,12): y<4 -> q (normalize * 0.125 -> Qdst);
//   y>=4 -> kv; m<512: k normalize -> Kdst; m>=512: v normalize*gw -> Vdst.
// ---------------------------------------------------------------------------
__global__ __launch_bounds__(256, 2) void gemm_mfma(
    const ushort_t* __restrict__ Aq, const ushort_t* __restrict__ BTq,
    const float* __restrict__ biasq, const ushort_t* __restrict__ Akv,
    const ushort_t* __restrict__ BTkv, const float* __restrict__ biaskv,
    int mode, float* __restrict__ Out, const float* __restrict__ resid,
    ushort_t* __restrict__ Qdst, ushort_t* __restrict__ Kdst,
    ushort_t* __restrict__ Vdst, const float* __restrict__ gwp) {
  __shared__ alignas(16) ushort_t As[128 * 32];
  __shared__ alignas(16) ushort_t Bs[128 * 32];
  int tid = threadIdx.x;
  int w = tid >> 6, lane = tid & 63, l15 = lane & 15, q = lane >> 4;
  int n0 = blockIdx.x * 128, bt = blockIdx.z;
  int wm = (w >> 1) * 64, wn = (w & 1) * 64;

  const ushort_t* A;
  const ushort_t* BT;
  const float* bias;
  int m0, lmode;
  if (mode == 3) {
    if (blockIdx.y < 4) {
      A = Aq; BT = BTq; bias = biasq; lmode = 1; m0 = blockIdx.y * 128;
    } else {
      A = Akv; BT = BTkv; bias = biaskv; lmode = 2; m0 = (blockIdx.y - 4) * 128;
    }
  } else {
    A = Aq; BT = BTq; bias = biasq; lmode = 0; m0 = blockIdx.y * 128;
  }
  const ushort_t* Bbt = BT + (size_t)bt * C_ * C_;

  int c0 = w * 64 + lane, c1 = 256 + w * 64 + lane;
  const ushort_t* ag0 = A + (size_t)(m0 + (c0 >> 2)) * 512 + (c0 & 3) * 8;
  const ushort_t* ag1 = A + (size_t)(m0 + (c1 >> 2)) * 512 + (c1 & 3) * 8;
  const ushort_t* bg0 = Bbt + (size_t)(n0 + (c0 >> 2)) * 512 + (c0 & 3) * 8;
  const ushort_t* bg1 = Bbt + (size_t)(n0 + (c1 >> 2)) * 512 + (c1 & 3) * 8;
  ushort_t* la0 = As + (size_t)(w * 64) * 8;
  ushort_t* la1 = As + (size_t)(256 + w * 64) * 8;
  ushort_t* lb0 = Bs + (size_t)(w * 64) * 8;
  ushort_t* lb1 = Bs + (size_t)(256 + w * 64) * 8;

  f4 acc[4][4];
#pragma unroll
  for (int i = 0; i < 4; ++i)
#pragma unroll
    for (int j = 0; j < 4; ++j) acc[i][j] = (f4){0.f, 0.f, 0.f, 0.f};

  for (int k0 = 0; k0 < 512; k0 += 32) {
    __syncthreads();
    GLOAD_LDS(ag0 + k0, la0);
    GLOAD_LDS(ag1 + k0, la1);
    GLOAD_LDS(bg0 + k0, lb0);
    GLOAD_LDS(bg1 + k0, lb1);
    __syncthreads();
    short8 af[4], bf[4];
#pragma unroll
    for (int mt = 0; mt < 4; ++mt)
      af[mt] = *(const short8*)&As[(size_t)(wm + mt * 16 + l15) * 32 + q * 8];
#pragma unroll
    for (int nt = 0; nt < 4; ++nt)
      bf[nt] = *(const short8*)&Bs[(size_t)(wn + nt * 16 + l15) * 32 + q * 8];
#pragma unroll
    for (int mt = 0; mt < 4; ++mt)
#pragma unroll
      for (int nt = 0; nt < 4; ++nt)
        acc[mt][nt] =
            __builtin_amdgcn_mfma_f32_16x16x32_bf16(af[mt], bf[nt], acc[mt][nt], 0, 0, 0);
  }

#pragma unroll
  for (int mt = 0; mt < 4; ++mt)
#pragma unroll
    for (int r = 0; r < 4; ++r) {
      float bb = bias[m0 + wm + mt * 16 + q * 4 + r];
#pragma unroll
      for (int nt = 0; nt < 4; ++nt) acc[mt][nt][r] += bb;
    }

  if (lmode == 0) {
    int b = bt >> 3, t = bt & 7;
    float* Ob = Out + (size_t)b * (C_ * T_ * L_) + (size_t)t * L_;
    const float* Rb = resid + (size_t)b * (C_ * T_ * L_) + (size_t)t * L_;
#pragma unroll
    for (int mt = 0; mt < 4; ++mt)
#pragma unroll
      for (int r = 0; r < 4; ++r) {
        size_t ro = (size_t)(m0 + wm + mt * 16 + q * 4 + r) * (T_ * L_);
#pragma unroll
        for (int nt = 0; nt < 4; ++nt) {
          int n = n0 + wn + nt * 16 + l15;
          Ob[ro + n] = acc[mt][nt][r] + Rb[ro + n];
        }
      }
    return;
  }

  // normalization over the wave's 64 m-rows (= one full head) per column
  float scale[4];
#pragma unroll
  for (int nt = 0; nt < 4; ++nt) {
    float s = 0.f;
#pragma unroll
    for (int mt = 0; mt < 4; ++mt)
#pragma unroll
      for (int r = 0; r < 4; ++r) s += acc[mt][nt][r] * acc[mt][nt][r];
    s += __shfl_xor(s, 16);
    s += __shfl_xor(s, 32);
    scale[nt] = s;
  }
  int hh = ((m0 + wm) >> 6) & 7;
  bool isv = (lmode == 2) && (m0 + wm >= 512);
  float mult = isv ? gwp[bt * H_ + hh] : (lmode == 1 ? 0.125f : 1.0f);
#pragma unroll
  for (int nt = 0; nt < 4; ++nt)
    scale[nt] = mult / fmaxf(sqrtf(scale[nt]), 1e-12f);

  if (!isv) {
    ushort_t* Db = (lmode == 1 ? Qdst : Kdst) + (size_t)(bt * H_ + hh) * 512 * 64;
#pragma unroll
    for (int nt = 0; nt < 4; ++nt) {
      int l = n0 + wn + nt * 16 + l15;
      ushort_t* rowp = Db + (size_t)l * 64;
#pragma unroll
      for (int mt = 0; mt < 4; ++mt) {
        uint2 pk;
        pk.x = pack_bf16(acc[mt][nt][0] * scale[nt], acc[mt][nt][1] * scale[nt]);
        pk.y = pack_bf16(acc[mt][nt][2] * scale[nt], acc[mt][nt][3] * scale[nt]);
        *(uint2*)&rowp[mt * 16 + q * 4] = pk;
      }
    }
  } else {
    ushort_t* Vb = Vdst + (size_t)(bt * H_ + hh) * 64 * 512;
#pragma unroll
    for (int mt = 0; mt < 4; ++mt)
#pragma unroll
      for (int r = 0; r < 4; ++r) {
        int d = mt * 16 + q * 4 + r;
        ushort_t* rp = Vb + (size_t)d * 512 + n0 + wn;
#pragma unroll
        for (int nt = 0; nt < 4; ++nt)
          rp[nt * 16 + l15] = bf16_1(acc[mt][nt][r] * scale[nt]);
      }
  }
}

// Flash MFMA attention, one block per (qblk,h,bt): 512 threads = 8 waves,
// 32 queries per wave (2 x 16-i frags). No LDS/barriers; K/V frags straight
// to registers. Live set ~122 unified regs -> 2 blocks/CU at bounds(512,2)
// (R5's failure was the ",4" bound squeezing to 64 regs; R6's was +64 reg
// double-buffer spilling to scratch). No-max softmax exact: |s| <= 0.125.
__global__ __launch_bounds__(512, 2) void attn_kernel(
    const ushort_t* __restrict__ Qbf, const ushort_t* __restrict__ Kbf,
    const ushort_t* __restrict__ Vbf, const float* __restrict__ gwp,
    ushort_t* __restrict__ obfT) {
  int tid = threadIdx.x;
  int w = tid >> 6, lane = tid & 63, l15 = lane & 15, q = lane >> 4;
  int qb = blockIdx.x, h = blockIdx.y, bt = blockIdx.z;
  int iw = qb * 256 + w * 32;  // wave's first query

  const ushort_t* Qg = Qbf + (size_t)(bt * H_ + h) * 512 * 64;
  const ushort_t* Kg = Kbf + (size_t)(bt * H_ + h) * 512 * 64;
  const ushort_t* Vg = Vbf + (size_t)(bt * H_ + h) * 64 * 512;

  short8 qf[2][2];
#pragma unroll
  for (int f = 0; f < 2; ++f) {
    const ushort_t* qrow = Qg + (size_t)(iw + f * 16 + l15) * 64;
    qf[f][0] = *(const short8*)&qrow[q * 8];
    qf[f][1] = *(const short8*)&qrow[32 + q * 8];
  }

  f4 acc[2][4];
#pragma unroll
  for (int f = 0; f < 2; ++f)
#pragma unroll
    for (int dt = 0; dt < 4; ++dt) acc[f][dt] = (f4){0.f, 0.f, 0.f, 0.f};
  float lsum[2] = {0.f, 0.f};
  bool hi_half = (lane >= 32);
  int qh2 = (q & 1) * 2;

  for (int j0 = 0; j0 < 512; j0 += 64) {
    short8 kf[4][2], vf[2][4];
#pragma unroll
    for (int jt = 0; jt < 4; ++jt) {
      const ushort_t* krow = Kg + (size_t)(j0 + jt * 16 + l15) * 64;
      kf[jt][0] = *(const short8*)&krow[q * 8];
      kf[jt][1] = *(const short8*)&krow[32 + q * 8];
    }
#pragma unroll
    for (int ks2 = 0; ks2 < 2; ++ks2)
#pragma unroll
      for (int dt = 0; dt < 4; ++dt)
        vf[ks2][dt] = *(const short8*)(Vg + (size_t)(dt * 16 + l15) * 512 + j0 +
                                       ks2 * 32 + q * 8);

#pragma unroll
    for (int f = 0; f < 2; ++f) {
      // S^T tiles (16j x 16i), C-layout: col=i(l15), row=j(q*4+r)
      f4 sc[4];
#pragma unroll
      for (int jt = 0; jt < 4; ++jt) {
        f4 c = {0.f, 0.f, 0.f, 0.f};
        c = __builtin_amdgcn_mfma_f32_16x16x32_bf16(kf[jt][0], qf[f][0], c, 0, 0, 0);
        c = __builtin_amdgcn_mfma_f32_16x16x32_bf16(kf[jt][1], qf[f][1], c, 0, 0, 0);
        sc[jt] = c;
      }
      float ls = 0.f;
#pragma unroll
      for (int jt = 0; jt < 4; ++jt)
#pragma unroll
        for (int r = 0; r < 4; ++r) {
          float p = __expf(sc[jt][r]);
          sc[jt][r] = p;
          ls += p;
        }
      lsum[f] += ls;

      unsigned pk01[4], pk23[4];
#pragma unroll
      for (int jt = 0; jt < 4; ++jt) {
        pk01[jt] = pack_bf16(sc[jt][0], sc[jt][1]);
        pk23[jt] = pack_bf16(sc[jt][2], sc[jt][3]);
      }
      // PV: O^T += V^T . P^T  (P^T shuffled into B-operand layout)
#pragma unroll
      for (int ks2 = 0; ks2 < 2; ++ks2) {
        union { unsigned u[4]; short8 s; } bu;
#pragma unroll
        for (int r = 0; r < 4; ++r) {
          int src = (qh2 + (r >> 1)) * 16 + l15;
          unsigned pl = (r & 1) ? pk23[ks2 * 2] : pk01[ks2 * 2];
          unsigned ph = (r & 1) ? pk23[ks2 * 2 + 1] : pk01[ks2 * 2 + 1];
          unsigned lo = __shfl(pl, src);
          unsigned hi = __shfl(ph, src);
          bu.u[r] = hi_half ? hi : lo;
        }
#pragma unroll
        for (int dt = 0; dt < 4; ++dt)
          acc[f][dt] = __builtin_amdgcn_mfma_f32_16x16x32_bf16(vf[ks2][dt], bu.s,
                                                               acc[f][dt], 0, 0, 0);
      }
    }
  }

  // epilogue: reduce l-sums, *gw, store bf16 to obfT[l][c]
  float g = gwp[bt * H_ + h];
#pragma unroll
  for (int f = 0; f < 2; ++f) {
    float ls = lsum[f];
    ls += __shfl_xor(ls, 16);
    ls += __shfl_xor(ls, 32);
    float inv = g / ls;
    int iglob = iw + f * 16 + l15;
    ushort_t* ob = obfT + ((size_t)(bt * 512 + iglob)) * 512 + h * 64;
#pragma unroll
    for (int dt = 0; dt < 4; ++dt) {
      uint2 pk;
      pk.x = pack_bf16(acc[f][dt][0] * inv, acc[f][dt][1] * inv);
      pk.y = pack_bf16(acc[f][dt][2] * inv, acc[f][dt][3] * inv);
      *(uint2*)&ob[dt * 16 + q * 4] = pk;
    }
  }
}

extern "C" void kernel_launch(void* const* d_in, const int* in_sizes, int n_in,
                              void* d_out, int out_size, void* d_ws, size_t ws_size,
                              hipStream_t stream) {
  const float* e   = (const float*)d_in[0];
  const float* x   = (const float*)d_in[1];
  const float* Wq  = (const float*)d_in[2];
  const float* bq  = (const float*)d_in[3];
  const float* Wkv = (const float*)d_in[4];
  const float* bkv = (const float*)d_in[5];
  const float* Wm  = (const float*)d_in[6];
  const float* bm  = (const float*)d_in[7];
  const float* Wg1 = (const float*)d_in[8];
  const float* bg1 = (const float*)d_in[9];
  const float* Wg2 = (const float*)d_in[10];
  const float* bg2 = (const float*)d_in[11];
  float* out = (float*)d_out;

  float* ws = (float*)d_ws;
  float* pooled = ws;                  // 16384
  float* gwp    = ws + 16384;          // 256
  float* h1buf  = ws + 16640;          // 16384
  float* fb     = ws + 33024;
  ushort_t* ebfT = (ushort_t*)(fb);
  ushort_t* xbfT = (ushort_t*)(fb + 1 * 4194304);
  ushort_t* Qbf  = (ushort_t*)(fb + 2 * 4194304);
  ushort_t* Kbf  = (ushort_t*)(fb + 3 * 4194304);
  ushort_t* Vbf  = (ushort_t*)(fb + 4 * 4194304);
  ushort_t* obfT = (ushort_t*)(fb + 5 * 4194304);
  ushort_t* Wqb  = (ushort_t*)(fb + 6 * 4194304);
  ushort_t* Wkvb = Wqb + 262144;
  ushort_t* Wmb  = Wkvb + 524288;

  hipMemsetAsync(pooled, 0, 16384 * sizeof(float), stream);
  cvt3_kernel<<<dim3(512), dim3(256), 0, stream>>>(Wq, Wkv, Wm, Wqb, Wkvb, Wmb);
  tconv_kernel<<<dim3(8, 8, 64), dim3(256), 0, stream>>>(e, x, ebfT, xbfT, pooled);
  gate1_kernel<<<dim3(128, 32), dim3(256), 0, stream>>>(pooled, Wg1, bg1, h1buf);
  gate2_kernel<<<dim3(32), dim3(256), 0, stream>>>(h1buf, Wg2, bg2, gwp);
  // fused q + kv projections (normalize epilogues) -> Qbf, Kbf, Vbf
  gemm_mfma<<<dim3(4, 12, 32), dim3(256), 0, stream>>>(
      Wqb, ebfT, bq, Wkvb, xbfT, bkv, 3, nullptr, nullptr, Qbf, Kbf, Vbf, gwp);
  // attention -> obfT (two query-blocks per (h,bt), bounds(512,2))
  attn_kernel<<<dim3(2, H_, 32), dim3(512), 0, stream>>>(Qbf, Kbf, Vbf, gwp, obfT);
  // output projection + bias + residual -> out
  gemm_mfma<<<dim3(4, 4, 32), dim3(256), 0, stream>>>(
      Wmb, obfT, bm, nullptr, nullptr, nullptr, 0, out, x, nullptr, nullptr,
      nullptr, gwp);
}

// Round 8
// 258.520 us; speedup vs baseline: 1.6816x; 1.0488x over previous
//
#include <hip/hip_runtime.h>
#include <math.h>

#define B_ 4
#define C_ 512
#define T_ 8
#define L_ 512
#define H_ 8
#define HD_ 64

typedef unsigned short ushort_t;
using short8 = __attribute__((ext_vector_type(8))) short;
using f4 = __attribute__((ext_vector_type(4))) float;

#define GLOAD_LDS(gp, lp)                                                      \
  __builtin_amdgcn_global_load_lds(                                            \
      (const __attribute__((address_space(1))) unsigned int*)(gp),             \
      (__attribute__((address_space(3))) unsigned int*)(lp), 16, 0, 0)

// RNE float->bf16 pack (a -> low 16, b -> high 16). Finite inputs only.
__device__ __forceinline__ unsigned pack_bf16(float a, float b) {
  union { float f; unsigned u; } ua, ub;
  ua.f = a; ub.f = b;
  unsigned ra = (ua.u + 0x7FFFu + ((ua.u >> 16) & 1u)) >> 16;
  unsigned rb = (ub.u + 0x7FFFu + ((ub.u >> 16) & 1u)) >> 16;
  return (rb << 16) | (ra & 0xFFFFu);
}
__device__ __forceinline__ ushort_t bf16_1(float a) {
  union { float f; unsigned u; } ua; ua.f = a;
  return (ushort_t)((ua.u + 0x7FFFu + ((ua.u >> 16) & 1u)) >> 16);
}

// ---------------------------------------------------------------------------
// Workspace: pooled 16384 | gwp 256 | h1 16384 | bf16 buffers:
//   ebfT,xbfT,Qbf,Kbf,Vbf,obfT 6x4194304 fl | Wqb 131072 | Wkvb 262144 | Wmb 131072
// Layouts: ebfT/xbfT/obfT = [bt][l][c] bf16 ; Qbf/Kbf = [bt][h][l][d]
//          (pre-normalized; Q also * 0.125*log2(e)) ; Vbf = [bt][h][d][l] (*gw)
// ---------------------------------------------------------------------------

// h1[bt][row] = tanh(dot(Wg1[row], pooled[bt]) + bg1[row]); one wave per row.
__global__ __launch_bounds__(256) void gate1_kernel(const float* __restrict__ pooled,
                                                    const float* __restrict__ Wg1,
                                                    const float* __restrict__ bg1,
                                                    float* __restrict__ h1) {
  int w = threadIdx.x >> 6, lane = threadIdx.x & 63;
  int row = blockIdx.x * 4 + w;
  int bt = blockIdx.y;
  const float* wr = Wg1 + (size_t)row * C_;
  const float* pr = pooled + bt * C_;
  float s = 0.f;
#pragma unroll
  for (int i = 0; i < 8; ++i) s += wr[lane + i * 64] * pr[lane + i * 64];
#pragma unroll
  for (int off = 32; off > 0; off >>= 1) s += __shfl_down(s, off, 64);
  if (lane == 0) h1[bt * C_ + row] = tanhf(s + bg1[row]);
}

__global__ __launch_bounds__(256) void gate2_kernel(const float* __restrict__ h1,
                                                    const float* __restrict__ Wg2,
                                                    const float* __restrict__ bg2,
                                                    float* __restrict__ gwp) {
  __shared__ float part[256];
  __shared__ float gl[H_];
  int bt = blockIdx.x, tid = threadIdx.x;
  int h = tid >> 5, s = tid & 31;
  const float* w2 = Wg2 + (size_t)h * C_;
  const float* hb = h1 + bt * C_;
  float p = 0.f;
  for (int c = s; c < C_; c += 32) p += w2[c] * hb[c];
  part[tid] = p;
  __syncthreads();
  if (tid < H_) {
    float a = bg2[tid];
    for (int i = 0; i < 32; ++i) a += part[tid * 32 + i];
    gl[tid] = a;
  }
  __syncthreads();
  if (tid == 0) {
    float m = -1e30f;
    for (int i = 0; i < H_; ++i) m = fmaxf(m, gl[i]);
    float sum = 0.f;
    float ex[H_];
    for (int i = 0; i < H_; ++i) { ex[i] = expf(gl[i] - m); sum += ex[i]; }
    for (int i = 0; i < H_; ++i) gwp[bt * H_ + i] = ex[i] / sum;
  }
}

// fp32 -> bf16 for all three weight matrices in one launch.
__global__ __launch_bounds__(256) void cvt3_kernel(const float* __restrict__ Wq,
                                                   const float* __restrict__ Wkv,
                                                   const float* __restrict__ Wm,
                                                   ushort_t* __restrict__ dWq,
                                                   ushort_t* __restrict__ dWkv,
                                                   ushort_t* __restrict__ dWm) {
  int i = (blockIdx.x * 256 + threadIdx.x) * 8;
  const float* s;
  ushort_t* d;
  int off;
  if (i < 262144)      { s = Wq;  d = dWq;  off = i; }
  else if (i < 786432) { s = Wkv; d = dWkv; off = i - 262144; }
  else                 { s = Wm;  d = dWm;  off = i - 786432; }
  float4 a = *(const float4*)(s + off);
  float4 b = *(const float4*)(s + off + 4);
  uint4 o;
  o.x = pack_bf16(a.x, a.y); o.y = pack_bf16(a.z, a.w);
  o.z = pack_bf16(b.x, b.y); o.w = pack_bf16(b.z, b.w);
  *(uint4*)(d + off) = o;
}

// Transpose-convert both e and x in one launch: grid z 0..63.
// z<32: src=e -> ebfT (+ pooled atomics); z>=32: src=x -> xbfT.
__global__ __launch_bounds__(256) void tconv_kernel(const float* __restrict__ e,
                                                    const float* __restrict__ x,
                                                    ushort_t* __restrict__ ebfT,
                                                    ushort_t* __restrict__ xbfT,
                                                    float* __restrict__ pooled) {
  __shared__ float tb[64][65];
  int tid = threadIdx.x;
  bool isE = blockIdx.z < 32;
  int bt = isE ? blockIdx.z : blockIdx.z - 32;
  const float* src = isE ? e : x;
  ushort_t* dst = isE ? ebfT : xbfT;
  int b = bt >> 3, t = bt & 7;
  int c0 = blockIdx.y * 64, l0 = blockIdx.x * 64;
  const float* sp = src + (((size_t)(b * C_ + c0) * T_) + t) * L_ + l0;
  int j = tid & 63, i0 = tid >> 6;
#pragma unroll
  for (int p = 0; p < 16; ++p) {
    int i = p * 4 + i0;
    tb[i][j] = sp[(size_t)i * (T_ * L_) + j];
  }
  __syncthreads();
  if (isE) {
    int c = tid >> 2, part = tid & 3;
    float s = 0.f;
#pragma unroll
    for (int k = 0; k < 16; ++k) s += tb[c][part * 16 + k];
    s += __shfl_down(s, 1);
    s += __shfl_down(s, 2);
    if (part == 0) atomicAdd(&pooled[bt * C_ + c0 + c], s * (1.0f / L_));
  }
  int ii = (tid & 31) * 2, jj0 = tid >> 5;
  ushort_t* dp = dst + ((size_t)bt * L_ + l0) * C_ + c0;
#pragma unroll
  for (int p = 0; p < 8; ++p) {
    int jj = p * 8 + jj0;
    *(unsigned*)(dp + (size_t)jj * C_ + ii) = pack_bf16(tb[ii][jj], tb[ii + 1][jj]);
  }
}

// ---------------------------------------------------------------------------
// bf16 MFMA GEMM: C[m][n] = A[m][k] . BT[n][k], K=512, 128x128 tile, BK=32.
// mode 0: Out fp32 (B,C,T,L) = C + bias[m] + resid   (A/BT/bias args, grid y=4)
// mode 3: fused qkv. grid y in [0,12): y<4 -> q (normalize * 0.125*log2e -> Qdst);
//   y>=4 -> kv; m<512: k normalize -> Kdst; m>=512: v normalize*gw -> Vdst.
// ---------------------------------------------------------------------------
__global__ __launch_bounds__(256, 2) void gemm_mfma(
    const ushort_t* __restrict__ Aq, const ushort_t* __restrict__ BTq,
    const float* __restrict__ biasq, const ushort_t* __restrict__ Akv,
    const ushort_t* __restrict__ BTkv, const float* __restrict__ biaskv,
    int mode, float* __restrict__ Out, const float* __restrict__ resid,
    ushort_t* __restrict__ Qdst, ushort_t* __restrict__ Kdst,
    ushort_t* __restrict__ Vdst, const float* __restrict__ gwp) {
  __shared__ alignas(16) ushort_t As[128 * 32];
  __shared__ alignas(16) ushort_t Bs[128 * 32];
  int tid = threadIdx.x;
  int w = tid >> 6, lane = tid & 63, l15 = lane & 15, q = lane >> 4;
  int n0 = blockIdx.x * 128, bt = blockIdx.z;
  int wm = (w >> 1) * 64, wn = (w & 1) * 64;

  const ushort_t* A;
  const ushort_t* BT;
  const float* bias;
  int m0, lmode;
  if (mode == 3) {
    if (blockIdx.y < 4) {
      A = Aq; BT = BTq; bias = biasq; lmode = 1; m0 = blockIdx.y * 128;
    } else {
      A = Akv; BT = BTkv; bias = biaskv; lmode = 2; m0 = (blockIdx.y - 4) * 128;
    }
  } else {
    A = Aq; BT = BTq; bias = biasq; lmode = 0; m0 = blockIdx.y * 128;
  }
  const ushort_t* Bbt = BT + (size_t)bt * C_ * C_;

  int c0 = w * 64 + lane, c1 = 256 + w * 64 + lane;
  const ushort_t* ag0 = A + (size_t)(m0 + (c0 >> 2)) * 512 + (c0 & 3) * 8;
  const ushort_t* ag1 = A + (size_t)(m0 + (c1 >> 2)) * 512 + (c1 & 3) * 8;
  const ushort_t* bg0 = Bbt + (size_t)(n0 + (c0 >> 2)) * 512 + (c0 & 3) * 8;
  const ushort_t* bg1 = Bbt + (size_t)(n0 + (c1 >> 2)) * 512 + (c1 & 3) * 8;
  ushort_t* la0 = As + (size_t)(w * 64) * 8;
  ushort_t* la1 = As + (size_t)(256 + w * 64) * 8;
  ushort_t* lb0 = Bs + (size_t)(w * 64) * 8;
  ushort_t* lb1 = Bs + (size_t)(256 + w * 64) * 8;

  f4 acc[4][4];
#pragma unroll
  for (int i = 0; i < 4; ++i)
#pragma unroll
    for (int j = 0; j < 4; ++j) acc[i][j] = (f4){0.f, 0.f, 0.f, 0.f};

  for (int k0 = 0; k0 < 512; k0 += 32) {
    __syncthreads();
    GLOAD_LDS(ag0 + k0, la0);
    GLOAD_LDS(ag1 + k0, la1);
    GLOAD_LDS(bg0 + k0, lb0);
    GLOAD_LDS(bg1 + k0, lb1);
    __syncthreads();
    short8 af[4], bf[4];
#pragma unroll
    for (int mt = 0; mt < 4; ++mt)
      af[mt] = *(const short8*)&As[(size_t)(wm + mt * 16 + l15) * 32 + q * 8];
#pragma unroll
    for (int nt = 0; nt < 4; ++nt)
      bf[nt] = *(const short8*)&Bs[(size_t)(wn + nt * 16 + l15) * 32 + q * 8];
#pragma unroll
    for (int mt = 0; mt < 4; ++mt)
#pragma unroll
      for (int nt = 0; nt < 4; ++nt)
        acc[mt][nt] =
            __builtin_amdgcn_mfma_f32_16x16x32_bf16(af[mt], bf[nt], acc[mt][nt], 0, 0, 0);
  }

#pragma unroll
  for (int mt = 0; mt < 4; ++mt)
#pragma unroll
    for (int r = 0; r < 4; ++r) {
      float bb = bias[m0 + wm + mt * 16 + q * 4 + r];
#pragma unroll
      for (int nt = 0; nt < 4; ++nt) acc[mt][nt][r] += bb;
    }

  if (lmode == 0) {
    int b = bt >> 3, t = bt & 7;
    float* Ob = Out + (size_t)b * (C_ * T_ * L_) + (size_t)t * L_;
    const float* Rb = resid + (size_t)b * (C_ * T_ * L_) + (size_t)t * L_;
#pragma unroll
    for (int mt = 0; mt < 4; ++mt)
#pragma unroll
      for (int r = 0; r < 4; ++r) {
        size_t ro = (size_t)(m0 + wm + mt * 16 + q * 4 + r) * (T_ * L_);
#pragma unroll
        for (int nt = 0; nt < 4; ++nt) {
          int n = n0 + wn + nt * 16 + l15;
          Ob[ro + n] = acc[mt][nt][r] + Rb[ro + n];
        }
      }
    return;
  }

  // normalization over the wave's 64 m-rows (= one full head) per column
  float scale[4];
#pragma unroll
  for (int nt = 0; nt < 4; ++nt) {
    float s = 0.f;
#pragma unroll
    for (int mt = 0; mt < 4; ++mt)
#pragma unroll
      for (int r = 0; r < 4; ++r) s += acc[mt][nt][r] * acc[mt][nt][r];
    s += __shfl_xor(s, 16);
    s += __shfl_xor(s, 32);
    scale[nt] = s;
  }
  int hh = ((m0 + wm) >> 6) & 7;
  bool isv = (lmode == 2) && (m0 + wm >= 512);
  // q scale folds 1/sqrt(hd)=0.125 AND log2(e) (attn softmax uses exp2)
  float mult = isv ? gwp[bt * H_ + hh]
                   : (lmode == 1 ? 0.125f * 1.44269504088896f : 1.0f);
#pragma unroll
  for (int nt = 0; nt < 4; ++nt)
    scale[nt] = mult / fmaxf(sqrtf(scale[nt]), 1e-12f);

  if (!isv) {
    ushort_t* Db = (lmode == 1 ? Qdst : Kdst) + (size_t)(bt * H_ + hh) * 512 * 64;
#pragma unroll
    for (int nt = 0; nt < 4; ++nt) {
      int l = n0 + wn + nt * 16 + l15;
      ushort_t* rowp = Db + (size_t)l * 64;
#pragma unroll
      for (int mt = 0; mt < 4; ++mt) {
        uint2 pk;
        pk.x = pack_bf16(acc[mt][nt][0] * scale[nt], acc[mt][nt][1] * scale[nt]);
        pk.y = pack_bf16(acc[mt][nt][2] * scale[nt], acc[mt][nt][3] * scale[nt]);
        *(uint2*)&rowp[mt * 16 + q * 4] = pk;
      }
    }
  } else {
    ushort_t* Vb = Vdst + (size_t)(bt * H_ + hh) * 64 * 512;
#pragma unroll
    for (int mt = 0; mt < 4; ++mt)
#pragma unroll
      for (int r = 0; r < 4; ++r) {
        int d = mt * 16 + q * 4 + r;
        ushort_t* rp = Vb + (size_t)d * 512 + n0 + wn;
#pragma unroll
        for (int nt = 0; nt < 4; ++nt)
          rp[nt * 16 + l15] = bf16_1(acc[mt][nt][r] * scale[nt]);
      }
  }
}

// Flash MFMA attention, LDS-staged + double-buffered. Block = 256 thr (4
// waves) handling 256 queries of one (bt,h); grid (2,H,32) -> 2 blocks/CU
// (LDS 32KB, regs ~200). Per tile: stage K(8KB)+V(8KB) via global_load_lds
// right after the barrier, compute 4 f-frags/wave on the other buffer.
// XOR-swizzled LDS (R3-verified addressing). Softmax via exp2 (log2e folded
// into Q scale); no-max softmax exact since |s| <= 0.18.
__global__ __launch_bounds__(256, 2) void attn_kernel(
    const ushort_t* __restrict__ Qbf, const ushort_t* __restrict__ Kbf,
    const ushort_t* __restrict__ Vbf, const float* __restrict__ gwp,
    ushort_t* __restrict__ obfT) {
  __shared__ alignas(16) ushort_t Ka[2][64 * 64];
  __shared__ alignas(16) ushort_t Va[2][64 * 64];

  int tid = threadIdx.x;
  int w = tid >> 6, lane = tid & 63, l15 = lane & 15, q = lane >> 4;
  int qb = blockIdx.x, h = blockIdx.y, bt = blockIdx.z;
  int iw = qb * 256 + w * 64;  // wave's first query

  const ushort_t* Qg = Qbf + (size_t)(bt * H_ + h) * 512 * 64;
  const ushort_t* Kg = Kbf + (size_t)(bt * H_ + h) * 512 * 64;
  const ushort_t* Vg = Vbf + (size_t)(bt * H_ + h) * 64 * 512;

  // staging addresses: chunk c of 512 16B-chunks; LDS slot s of row r holds
  // global chunk s^(r&7) (XOR swizzle on the global side)
  int cA = tid, cB = tid + 256;
  const ushort_t* kgA = Kg + (size_t)(cA >> 3) * 64 + ((cA & 7) ^ ((cA >> 3) & 7)) * 8;
  const ushort_t* kgB = Kg + (size_t)(cB >> 3) * 64 + ((cB & 7) ^ ((cB >> 3) & 7)) * 8;
  const ushort_t* vgA = Vg + (size_t)(cA >> 3) * 512 + ((cA & 7) ^ ((cA >> 3) & 7)) * 8;
  const ushort_t* vgB = Vg + (size_t)(cB >> 3) * 512 + ((cB & 7) ^ ((cB >> 3) & 7)) * 8;

  short8 qf[4][2];
#pragma unroll
  for (int f = 0; f < 4; ++f) {
    const ushort_t* qrow = Qg + (size_t)(iw + f * 16 + l15) * 64;
    qf[f][0] = *(const short8*)&qrow[q * 8];
    qf[f][1] = *(const short8*)&qrow[32 + q * 8];
  }

  f4 acc[4][4];
#pragma unroll
  for (int f = 0; f < 4; ++f)
#pragma unroll
    for (int dt = 0; dt < 4; ++dt) acc[f][dt] = (f4){0.f, 0.f, 0.f, 0.f};
  float lsum[4] = {0.f, 0.f, 0.f, 0.f};
  bool hi_half = (lane >= 32);
  int qh2 = (q & 1) * 2;

  // prologue: stage tile 0 into buffer 0
  {
    ushort_t* lk = Ka[0] + (size_t)(w * 64) * 8;
    ushort_t* lk2 = Ka[0] + (size_t)(256 + w * 64) * 8;
    ushort_t* lv = Va[0] + (size_t)(w * 64) * 8;
    ushort_t* lv2 = Va[0] + (size_t)(256 + w * 64) * 8;
    GLOAD_LDS(kgA, lk);
    GLOAD_LDS(kgB, lk2);
    GLOAD_LDS(vgA, lv);
    GLOAD_LDS(vgB, lv2);
  }

  for (int jj = 0; jj < 8; ++jj) {
    const int cur = jj & 1;
    __syncthreads();  // drains vmcnt: buf[cur] staged; joins prev compute on buf[cur^1]
    if (jj < 7) {
      const int j0n = (jj + 1) * 64;
      ushort_t* lk = Ka[cur ^ 1] + (size_t)(w * 64) * 8;
      ushort_t* lk2 = Ka[cur ^ 1] + (size_t)(256 + w * 64) * 8;
      ushort_t* lv = Va[cur ^ 1] + (size_t)(w * 64) * 8;
      ushort_t* lv2 = Va[cur ^ 1] + (size_t)(256 + w * 64) * 8;
      GLOAD_LDS(kgA + (size_t)j0n * 64, lk);
      GLOAD_LDS(kgB + (size_t)j0n * 64, lk2);
      GLOAD_LDS(vgA + j0n, lv);
      GLOAD_LDS(vgB + j0n, lv2);
    }

    // read K/V fragments once per tile, reuse across 4 f
    short8 kf[4][2], vf[2][4];
#pragma unroll
    for (int jt = 0; jt < 4; ++jt) {
      int row = jt * 16 + l15;
      int swz = row & 7;
      kf[jt][0] = *(const short8*)&Ka[cur][row * 64 + ((q ^ swz) * 8)];
      kf[jt][1] = *(const short8*)&Ka[cur][row * 64 + (((4 + q) ^ swz) * 8)];
    }
#pragma unroll
    for (int ks2 = 0; ks2 < 2; ++ks2)
#pragma unroll
      for (int dt = 0; dt < 4; ++dt) {
        int row = dt * 16 + l15;
        vf[ks2][dt] =
            *(const short8*)&Va[cur][row * 64 + (((ks2 * 4 + q) ^ (row & 7)) * 8)];
      }

#pragma unroll
    for (int f = 0; f < 4; ++f) {
      // S^T tiles (16j x 16i), C-layout: col=i(l15), row=j(q*4+r)
      f4 sc[4];
#pragma unroll
      for (int jt = 0; jt < 4; ++jt) {
        f4 c = {0.f, 0.f, 0.f, 0.f};
        c = __builtin_amdgcn_mfma_f32_16x16x32_bf16(kf[jt][0], qf[f][0], c, 0, 0, 0);
        c = __builtin_amdgcn_mfma_f32_16x16x32_bf16(kf[jt][1], qf[f][1], c, 0, 0, 0);
        sc[jt] = c;
      }
      float ls = 0.f;
#pragma unroll
      for (int jt = 0; jt < 4; ++jt)
#pragma unroll
        for (int r = 0; r < 4; ++r) {
          float p = __builtin_exp2f(sc[jt][r]);  // log2e pre-folded into Q
          sc[jt][r] = p;
          ls += p;
        }
      lsum[f] += ls;

      unsigned pk01[4], pk23[4];
#pragma unroll
      for (int jt = 0; jt < 4; ++jt) {
        pk01[jt] = pack_bf16(sc[jt][0], sc[jt][1]);
        pk23[jt] = pack_bf16(sc[jt][2], sc[jt][3]);
      }
      // PV: O^T += V^T . P^T  (P^T shuffled into B-operand layout)
#pragma unroll
      for (int ks2 = 0; ks2 < 2; ++ks2) {
        union { unsigned u[4]; short8 s; } bu;
#pragma unroll
        for (int r = 0; r < 4; ++r) {
          int src = (qh2 + (r >> 1)) * 16 + l15;
          unsigned pl = (r & 1) ? pk23[ks2 * 2] : pk01[ks2 * 2];
          unsigned ph = (r & 1) ? pk23[ks2 * 2 + 1] : pk01[ks2 * 2 + 1];
          unsigned lo = __shfl(pl, src);
          unsigned hi = __shfl(ph, src);
          bu.u[r] = hi_half ? hi : lo;
        }
#pragma unroll
        for (int dt = 0; dt < 4; ++dt)
          acc[f][dt] = __builtin_amdgcn_mfma_f32_16x16x32_bf16(vf[ks2][dt], bu.s,
                                                               acc[f][dt], 0, 0, 0);
      }
    }
  }

  // epilogue: reduce l-sums, *gw, store bf16 to obfT[l][c]
  float g = gwp[bt * H_ + h];
#pragma unroll
  for (int f = 0; f < 4; ++f) {
    float ls = lsum[f];
    ls += __shfl_xor(ls, 16);
    ls += __shfl_xor(ls, 32);
    float inv = g / ls;
    int iglob = iw + f * 16 + l15;
    ushort_t* ob = obfT + ((size_t)(bt * 512 + iglob)) * 512 + h * 64;
#pragma unroll
    for (int dt = 0; dt < 4; ++dt) {
      uint2 pk;
      pk.x = pack_bf16(acc[f][dt][0] * inv, acc[f][dt][1] * inv);
      pk.y = pack_bf16(acc[f][dt][2] * inv, acc[f][dt][3] * inv);
      *(uint2*)&ob[dt * 16 + q * 4] = pk;
    }
  }
}

extern "C" void kernel_launch(void* const* d_in, const int* in_sizes, int n_in,
                              void* d_out, int out_size, void* d_ws, size_t ws_size,
                              hipStream_t stream) {
  const float* e   = (const float*)d_in[0];
  const float* x   = (const float*)d_in[1];
  const float* Wq  = (const float*)d_in[2];
  const float* bq  = (const float*)d_in[3];
  const float* Wkv = (const float*)d_in[4];
  const float* bkv = (const float*)d_in[5];
  const float* Wm  = (const float*)d_in[6];
  const float* bm  = (const float*)d_in[7];
  const float* Wg1 = (const float*)d_in[8];
  const float* bg1 = (const float*)d_in[9];
  const float* Wg2 = (const float*)d_in[10];
  const float* bg2 = (const float*)d_in[11];
  float* out = (float*)d_out;

  float* ws = (float*)d_ws;
  float* pooled = ws;                  // 16384
  float* gwp    = ws + 16384;          // 256
  float* h1buf  = ws + 16640;          // 16384
  float* fb     = ws + 33024;
  ushort_t* ebfT = (ushort_t*)(fb);
  ushort_t* xbfT = (ushort_t*)(fb + 1 * 4194304);
  ushort_t* Qbf  = (ushort_t*)(fb + 2 * 4194304);
  ushort_t* Kbf  = (ushort_t*)(fb + 3 * 4194304);
  ushort_t* Vbf  = (ushort_t*)(fb + 4 * 4194304);
  ushort_t* obfT = (ushort_t*)(fb + 5 * 4194304);
  ushort_t* Wqb  = (ushort_t*)(fb + 6 * 4194304);
  ushort_t* Wkvb = Wqb + 262144;
  ushort_t* Wmb  = Wkvb + 524288;

  hipMemsetAsync(pooled, 0, 16384 * sizeof(float), stream);
  cvt3_kernel<<<dim3(512), dim3(256), 0, stream>>>(Wq, Wkv, Wm, Wqb, Wkvb, Wmb);
  tconv_kernel<<<dim3(8, 8, 64), dim3(256), 0, stream>>>(e, x, ebfT, xbfT, pooled);
  gate1_kernel<<<dim3(128, 32), dim3(256), 0, stream>>>(pooled, Wg1, bg1, h1buf);
  gate2_kernel<<<dim3(32), dim3(256), 0, stream>>>(h1buf, Wg2, bg2, gwp);
  // fused q + kv projections (normalize epilogues) -> Qbf, Kbf, Vbf
  gemm_mfma<<<dim3(4, 12, 32), dim3(256), 0, stream>>>(
      Wqb, ebfT, bq, Wkvb, xbfT, bkv, 3, nullptr, nullptr, Qbf, Kbf, Vbf, gwp);
  // attention -> obfT (LDS double-buffered, 2 query-blocks per (h,bt))
  attn_kernel<<<dim3(2, H_, 32), dim3(256), 0, stream>>>(Qbf, Kbf, Vbf, gwp, obfT);
  // output projection + bias + residual -> out
  gemm_mfma<<<dim3(4, 4, 32), dim3(256), 0, stream>>>(
      Wmb, obfT, bm, nullptr, nullptr, nullptr, 0, out, x, nullptr, nullptr,
      nullptr, gwp);
}

// Round 9
// 248.488 us; speedup vs baseline: 1.7494x; 1.0404x over previous
//
#include <hip/hip_runtime.h>
#include <hip/hip_bf16.h>
#include <math.h>

#define B_ 4
#define C_ 512
#define T_ 8
#define L_ 512
#define H_ 8
#define HD_ 64

typedef unsigned short ushort_t;
using short8 = __attribute__((ext_vector_type(8))) short;
using f4 = __attribute__((ext_vector_type(4))) float;

#define GLOAD_LDS(gp, lp)                                                      \
  __builtin_amdgcn_global_load_lds(                                            \
      (const __attribute__((address_space(1))) unsigned int*)(gp),             \
      (__attribute__((address_space(3))) unsigned int*)(lp), 16, 0, 0)

// RNE float->bf16 pack (a -> low 16, b -> high 16). Finite inputs only.
__device__ __forceinline__ unsigned pack_bf16(float a, float b) {
  union { float f; unsigned u; } ua, ub;
  ua.f = a; ub.f = b;
  unsigned ra = (ua.u + 0x7FFFu + ((ua.u >> 16) & 1u)) >> 16;
  unsigned rb = (ub.u + 0x7FFFu + ((ub.u >> 16) & 1u)) >> 16;
  return (rb << 16) | (ra & 0xFFFFu);
}
// HW pack: v_cvt_pk_bf16_f32 (1 instr, RNE) — use on hot paths.
__device__ __forceinline__ unsigned pack2(float a, float b) {
  union { __hip_bfloat162 h; unsigned u; } cv;
  cv.h = __float22bfloat162_rn(make_float2(a, b));
  return cv.u;
}
__device__ __forceinline__ ushort_t bf16_1(float a) {
  union { float f; unsigned u; } ua; ua.f = a;
  return (ushort_t)((ua.u + 0x7FFFu + ((ua.u >> 16) & 1u)) >> 16);
}

// ---------------------------------------------------------------------------
// Workspace: pooled 16384 | gwp 256 | h1 16384 | bf16 buffers:
//   ebfT,xbfT,Qbf,Kbf,Vbf,obfT 6x4194304 fl | Wqb 131072 | Wkvb 262144 | Wmb 131072
// Layouts: ebfT/xbfT/obfT = [bt][l][c] bf16 ; Qbf/Kbf = [bt][h][l][d]
//          (pre-normalized; Q also * 0.125*log2(e)) ; Vbf = [bt][h][d][l] (*gw)
// ---------------------------------------------------------------------------

// h1[bt][row] = tanh(dot(Wg1[row], pooled[bt]) + bg1[row]); one wave per row.
__global__ __launch_bounds__(256) void gate1_kernel(const float* __restrict__ pooled,
                                                    const float* __restrict__ Wg1,
                                                    const float* __restrict__ bg1,
                                                    float* __restrict__ h1) {
  int w = threadIdx.x >> 6, lane = threadIdx.x & 63;
  int row = blockIdx.x * 4 + w;
  int bt = blockIdx.y;
  const float* wr = Wg1 + (size_t)row * C_;
  const float* pr = pooled + bt * C_;
  float s = 0.f;
#pragma unroll
  for (int i = 0; i < 8; ++i) s += wr[lane + i * 64] * pr[lane + i * 64];
#pragma unroll
  for (int off = 32; off > 0; off >>= 1) s += __shfl_down(s, off, 64);
  if (lane == 0) h1[bt * C_ + row] = tanhf(s + bg1[row]);
}

__global__ __launch_bounds__(256) void gate2_kernel(const float* __restrict__ h1,
                                                    const float* __restrict__ Wg2,
                                                    const float* __restrict__ bg2,
                                                    float* __restrict__ gwp) {
  __shared__ float part[256];
  __shared__ float gl[H_];
  int bt = blockIdx.x, tid = threadIdx.x;
  int h = tid >> 5, s = tid & 31;
  const float* w2 = Wg2 + (size_t)h * C_;
  const float* hb = h1 + bt * C_;
  float p = 0.f;
  for (int c = s; c < C_; c += 32) p += w2[c] * hb[c];
  part[tid] = p;
  __syncthreads();
  if (tid < H_) {
    float a = bg2[tid];
    for (int i = 0; i < 32; ++i) a += part[tid * 32 + i];
    gl[tid] = a;
  }
  __syncthreads();
  if (tid == 0) {
    float m = -1e30f;
    for (int i = 0; i < H_; ++i) m = fmaxf(m, gl[i]);
    float sum = 0.f;
    float ex[H_];
    for (int i = 0; i < H_; ++i) { ex[i] = expf(gl[i] - m); sum += ex[i]; }
    for (int i = 0; i < H_; ++i) gwp[bt * H_ + i] = ex[i] / sum;
  }
}

// fp32 -> bf16 for all three weight matrices in one launch.
__global__ __launch_bounds__(256) void cvt3_kernel(const float* __restrict__ Wq,
                                                   const float* __restrict__ Wkv,
                                                   const float* __restrict__ Wm,
                                                   ushort_t* __restrict__ dWq,
                                                   ushort_t* __restrict__ dWkv,
                                                   ushort_t* __restrict__ dWm) {
  int i = (blockIdx.x * 256 + threadIdx.x) * 8;
  const float* s;
  ushort_t* d;
  int off;
  if (i < 262144)      { s = Wq;  d = dWq;  off = i; }
  else if (i < 786432) { s = Wkv; d = dWkv; off = i - 262144; }
  else                 { s = Wm;  d = dWm;  off = i - 786432; }
  float4 a = *(const float4*)(s + off);
  float4 b = *(const float4*)(s + off + 4);
  uint4 o;
  o.x = pack_bf16(a.x, a.y); o.y = pack_bf16(a.z, a.w);
  o.z = pack_bf16(b.x, b.y); o.w = pack_bf16(b.z, b.w);
  *(uint4*)(d + off) = o;
}

// Transpose-convert both e and x in one launch: grid z 0..63.
// z<32: src=e -> ebfT (+ pooled atomics); z>=32: src=x -> xbfT.
__global__ __launch_bounds__(256) void tconv_kernel(const float* __restrict__ e,
                                                    const float* __restrict__ x,
                                                    ushort_t* __restrict__ ebfT,
                                                    ushort_t* __restrict__ xbfT,
                                                    float* __restrict__ pooled) {
  __shared__ float tb[64][65];
  int tid = threadIdx.x;
  bool isE = blockIdx.z < 32;
  int bt = isE ? blockIdx.z : blockIdx.z - 32;
  const float* src = isE ? e : x;
  ushort_t* dst = isE ? ebfT : xbfT;
  int b = bt >> 3, t = bt & 7;
  int c0 = blockIdx.y * 64, l0 = blockIdx.x * 64;
  const float* sp = src + (((size_t)(b * C_ + c0) * T_) + t) * L_ + l0;
  int j = tid & 63, i0 = tid >> 6;
#pragma unroll
  for (int p = 0; p < 16; ++p) {
    int i = p * 4 + i0;
    tb[i][j] = sp[(size_t)i * (T_ * L_) + j];
  }
  __syncthreads();
  if (isE) {
    int c = tid >> 2, part = tid & 3;
    float s = 0.f;
#pragma unroll
    for (int k = 0; k < 16; ++k) s += tb[c][part * 16 + k];
    s += __shfl_down(s, 1);
    s += __shfl_down(s, 2);
    if (part == 0) atomicAdd(&pooled[bt * C_ + c0 + c], s * (1.0f / L_));
  }
  int ii = (tid & 31) * 2, jj0 = tid >> 5;
  ushort_t* dp = dst + ((size_t)bt * L_ + l0) * C_ + c0;
#pragma unroll
  for (int p = 0; p < 8; ++p) {
    int jj = p * 8 + jj0;
    *(unsigned*)(dp + (size_t)jj * C_ + ii) = pack_bf16(tb[ii][jj], tb[ii + 1][jj]);
  }
}

// ---------------------------------------------------------------------------
// bf16 MFMA GEMM: C[m][n] = A[m][k] . BT[n][k], K=512, 128x128 tile, BK=32.
// mode 0: Out fp32 (B,C,T,L) = C + bias[m] + resid   (A/BT/bias args, grid y=4)
// mode 3: fused qkv. grid y in [0,12): y<4 -> q (normalize * 0.125*log2e -> Qdst);
//   y>=4 -> kv; m<512: k normalize -> Kdst; m>=512: v normalize*gw -> Vdst.
// ---------------------------------------------------------------------------
__global__ __launch_bounds__(256, 2) void gemm_mfma(
    const ushort_t* __restrict__ Aq, const ushort_t* __restrict__ BTq,
    const float* __restrict__ biasq, const ushort_t* __restrict__ Akv,
    const ushort_t* __restrict__ BTkv, const float* __restrict__ biaskv,
    int mode, float* __restrict__ Out, const float* __restrict__ resid,
    ushort_t* __restrict__ Qdst, ushort_t* __restrict__ Kdst,
    ushort_t* __restrict__ Vdst, const float* __restrict__ gwp) {
  __shared__ alignas(16) ushort_t As[128 * 32];
  __shared__ alignas(16) ushort_t Bs[128 * 32];
  int tid = threadIdx.x;
  int w = tid >> 6, lane = tid & 63, l15 = lane & 15, q = lane >> 4;
  int n0 = blockIdx.x * 128, bt = blockIdx.z;
  int wm = (w >> 1) * 64, wn = (w & 1) * 64;

  const ushort_t* A;
  const ushort_t* BT;
  const float* bias;
  int m0, lmode;
  if (mode == 3) {
    if (blockIdx.y < 4) {
      A = Aq; BT = BTq; bias = biasq; lmode = 1; m0 = blockIdx.y * 128;
    } else {
      A = Akv; BT = BTkv; bias = biaskv; lmode = 2; m0 = (blockIdx.y - 4) * 128;
    }
  } else {
    A = Aq; BT = BTq; bias = biasq; lmode = 0; m0 = blockIdx.y * 128;
  }
  const ushort_t* Bbt = BT + (size_t)bt * C_ * C_;

  int c0 = w * 64 + lane, c1 = 256 + w * 64 + lane;
  const ushort_t* ag0 = A + (size_t)(m0 + (c0 >> 2)) * 512 + (c0 & 3) * 8;
  const ushort_t* ag1 = A + (size_t)(m0 + (c1 >> 2)) * 512 + (c1 & 3) * 8;
  const ushort_t* bg0 = Bbt + (size_t)(n0 + (c0 >> 2)) * 512 + (c0 & 3) * 8;
  const ushort_t* bg1 = Bbt + (size_t)(n0 + (c1 >> 2)) * 512 + (c1 & 3) * 8;
  ushort_t* la0 = As + (size_t)(w * 64) * 8;
  ushort_t* la1 = As + (size_t)(256 + w * 64) * 8;
  ushort_t* lb0 = Bs + (size_t)(w * 64) * 8;
  ushort_t* lb1 = Bs + (size_t)(256 + w * 64) * 8;

  f4 acc[4][4];
#pragma unroll
  for (int i = 0; i < 4; ++i)
#pragma unroll
    for (int j = 0; j < 4; ++j) acc[i][j] = (f4){0.f, 0.f, 0.f, 0.f};

  for (int k0 = 0; k0 < 512; k0 += 32) {
    __syncthreads();
    GLOAD_LDS(ag0 + k0, la0);
    GLOAD_LDS(ag1 + k0, la1);
    GLOAD_LDS(bg0 + k0, lb0);
    GLOAD_LDS(bg1 + k0, lb1);
    __syncthreads();
    short8 af[4], bf[4];
#pragma unroll
    for (int mt = 0; mt < 4; ++mt)
      af[mt] = *(const short8*)&As[(size_t)(wm + mt * 16 + l15) * 32 + q * 8];
#pragma unroll
    for (int nt = 0; nt < 4; ++nt)
      bf[nt] = *(const short8*)&Bs[(size_t)(wn + nt * 16 + l15) * 32 + q * 8];
#pragma unroll
    for (int mt = 0; mt < 4; ++mt)
#pragma unroll
      for (int nt = 0; nt < 4; ++nt)
        acc[mt][nt] =
            __builtin_amdgcn_mfma_f32_16x16x32_bf16(af[mt], bf[nt], acc[mt][nt], 0, 0, 0);
  }

#pragma unroll
  for (int mt = 0; mt < 4; ++mt)
#pragma unroll
    for (int r = 0; r < 4; ++r) {
      float bb = bias[m0 + wm + mt * 16 + q * 4 + r];
#pragma unroll
      for (int nt = 0; nt < 4; ++nt) acc[mt][nt][r] += bb;
    }

  if (lmode == 0) {
    int b = bt >> 3, t = bt & 7;
    float* Ob = Out + (size_t)b * (C_ * T_ * L_) + (size_t)t * L_;
    const float* Rb = resid + (size_t)b * (C_ * T_ * L_) + (size_t)t * L_;
#pragma unroll
    for (int mt = 0; mt < 4; ++mt)
#pragma unroll
      for (int r = 0; r < 4; ++r) {
        size_t ro = (size_t)(m0 + wm + mt * 16 + q * 4 + r) * (T_ * L_);
#pragma unroll
        for (int nt = 0; nt < 4; ++nt) {
          int n = n0 + wn + nt * 16 + l15;
          Ob[ro + n] = acc[mt][nt][r] + Rb[ro + n];
        }
      }
    return;
  }

  // normalization over the wave's 64 m-rows (= one full head) per column
  float scale[4];
#pragma unroll
  for (int nt = 0; nt < 4; ++nt) {
    float s = 0.f;
#pragma unroll
    for (int mt = 0; mt < 4; ++mt)
#pragma unroll
      for (int r = 0; r < 4; ++r) s += acc[mt][nt][r] * acc[mt][nt][r];
    s += __shfl_xor(s, 16);
    s += __shfl_xor(s, 32);
    scale[nt] = s;
  }
  int hh = ((m0 + wm) >> 6) & 7;
  bool isv = (lmode == 2) && (m0 + wm >= 512);
  // q scale folds 1/sqrt(hd)=0.125 AND log2(e) (attn softmax uses exp2)
  float mult = isv ? gwp[bt * H_ + hh]
                   : (lmode == 1 ? 0.125f * 1.44269504088896f : 1.0f);
#pragma unroll
  for (int nt = 0; nt < 4; ++nt)
    scale[nt] = mult / fmaxf(sqrtf(scale[nt]), 1e-12f);

  if (!isv) {
    ushort_t* Db = (lmode == 1 ? Qdst : Kdst) + (size_t)(bt * H_ + hh) * 512 * 64;
#pragma unroll
    for (int nt = 0; nt < 4; ++nt) {
      int l = n0 + wn + nt * 16 + l15;
      ushort_t* rowp = Db + (size_t)l * 64;
#pragma unroll
      for (int mt = 0; mt < 4; ++mt) {
        uint2 pk;
        pk.x = pack_bf16(acc[mt][nt][0] * scale[nt], acc[mt][nt][1] * scale[nt]);
        pk.y = pack_bf16(acc[mt][nt][2] * scale[nt], acc[mt][nt][3] * scale[nt]);
        *(uint2*)&rowp[mt * 16 + q * 4] = pk;
      }
    }
  } else {
    ushort_t* Vb = Vdst + (size_t)(bt * H_ + hh) * 64 * 512;
#pragma unroll
    for (int mt = 0; mt < 4; ++mt)
#pragma unroll
      for (int r = 0; r < 4; ++r) {
        int d = mt * 16 + q * 4 + r;
        ushort_t* rp = Vb + (size_t)d * 512 + n0 + wn;
#pragma unroll
        for (int nt = 0; nt < 4; ++nt)
          rp[nt * 16 + l15] = bf16_1(acc[mt][nt][r] * scale[nt]);
      }
  }
}

// Flash MFMA attention, LDS-staged + double-buffered. Block = 256 thr (4
// waves) handling 128 queries (2 f-frags/wave); grid (4,H,32) = 1024 blocks
// -> up to 3 blocks/CU at launch_bounds(256,3) (LDS 96KB, ~170-reg cap; live
// set ~150 so no squeeze per R5 lesson). K/V tiles staged via global_load_lds
// with XOR swizzle; softmax via exp2 (log2e folded into Q); no-max softmax
// exact (|s| <= 0.18). Hot packs use v_cvt_pk_bf16_f32.
__global__ __launch_bounds__(256, 3) void attn_kernel(
    const ushort_t* __restrict__ Qbf, const ushort_t* __restrict__ Kbf,
    const ushort_t* __restrict__ Vbf, const float* __restrict__ gwp,
    ushort_t* __restrict__ obfT) {
  __shared__ alignas(16) ushort_t Ka[2][64 * 64];
  __shared__ alignas(16) ushort_t Va[2][64 * 64];

  int tid = threadIdx.x;
  int w = tid >> 6, lane = tid & 63, l15 = lane & 15, q = lane >> 4;
  int qb = blockIdx.x, h = blockIdx.y, bt = blockIdx.z;
  int iw = qb * 128 + w * 32;  // wave's first query

  const ushort_t* Qg = Qbf + (size_t)(bt * H_ + h) * 512 * 64;
  const ushort_t* Kg = Kbf + (size_t)(bt * H_ + h) * 512 * 64;
  const ushort_t* Vg = Vbf + (size_t)(bt * H_ + h) * 64 * 512;

  // staging addresses: chunk c of 512 16B-chunks; LDS slot s of row r holds
  // global chunk s^(r&7) (XOR swizzle on the global side)
  int cA = tid, cB = tid + 256;
  const ushort_t* kgA = Kg + (size_t)(cA >> 3) * 64 + ((cA & 7) ^ ((cA >> 3) & 7)) * 8;
  const ushort_t* kgB = Kg + (size_t)(cB >> 3) * 64 + ((cB & 7) ^ ((cB >> 3) & 7)) * 8;
  const ushort_t* vgA = Vg + (size_t)(cA >> 3) * 512 + ((cA & 7) ^ ((cA >> 3) & 7)) * 8;
  const ushort_t* vgB = Vg + (size_t)(cB >> 3) * 512 + ((cB & 7) ^ ((cB >> 3) & 7)) * 8;

  short8 qf[2][2];
#pragma unroll
  for (int f = 0; f < 2; ++f) {
    const ushort_t* qrow = Qg + (size_t)(iw + f * 16 + l15) * 64;
    qf[f][0] = *(const short8*)&qrow[q * 8];
    qf[f][1] = *(const short8*)&qrow[32 + q * 8];
  }

  f4 acc[2][4];
#pragma unroll
  for (int f = 0; f < 2; ++f)
#pragma unroll
    for (int dt = 0; dt < 4; ++dt) acc[f][dt] = (f4){0.f, 0.f, 0.f, 0.f};
  float lsum[2] = {0.f, 0.f};
  bool hi_half = (lane >= 32);
  int qh2 = (q & 1) * 2;

  // prologue: stage tile 0 into buffer 0
  {
    ushort_t* lk = Ka[0] + (size_t)(w * 64) * 8;
    ushort_t* lk2 = Ka[0] + (size_t)(256 + w * 64) * 8;
    ushort_t* lv = Va[0] + (size_t)(w * 64) * 8;
    ushort_t* lv2 = Va[0] + (size_t)(256 + w * 64) * 8;
    GLOAD_LDS(kgA, lk);
    GLOAD_LDS(kgB, lk2);
    GLOAD_LDS(vgA, lv);
    GLOAD_LDS(vgB, lv2);
  }

  for (int jj = 0; jj < 8; ++jj) {
    const int cur = jj & 1;
    __syncthreads();  // drains vmcnt: buf[cur] staged; joins prev compute on buf[cur^1]
    if (jj < 7) {
      const int j0n = (jj + 1) * 64;
      ushort_t* lk = Ka[cur ^ 1] + (size_t)(w * 64) * 8;
      ushort_t* lk2 = Ka[cur ^ 1] + (size_t)(256 + w * 64) * 8;
      ushort_t* lv = Va[cur ^ 1] + (size_t)(w * 64) * 8;
      ushort_t* lv2 = Va[cur ^ 1] + (size_t)(256 + w * 64) * 8;
      GLOAD_LDS(kgA + (size_t)j0n * 64, lk);
      GLOAD_LDS(kgB + (size_t)j0n * 64, lk2);
      GLOAD_LDS(vgA + j0n, lv);
      GLOAD_LDS(vgB + j0n, lv2);
    }

    // read K/V fragments once per tile, reuse across both f
    short8 kf[4][2], vf[2][4];
#pragma unroll
    for (int jt = 0; jt < 4; ++jt) {
      int row = jt * 16 + l15;
      int swz = row & 7;
      kf[jt][0] = *(const short8*)&Ka[cur][row * 64 + ((q ^ swz) * 8)];
      kf[jt][1] = *(const short8*)&Ka[cur][row * 64 + (((4 + q) ^ swz) * 8)];
    }
#pragma unroll
    for (int ks2 = 0; ks2 < 2; ++ks2)
#pragma unroll
      for (int dt = 0; dt < 4; ++dt) {
        int row = dt * 16 + l15;
        vf[ks2][dt] =
            *(const short8*)&Va[cur][row * 64 + (((ks2 * 4 + q) ^ (row & 7)) * 8)];
      }

#pragma unroll
    for (int f = 0; f < 2; ++f) {
      // S^T tiles (16j x 16i), C-layout: col=i(l15), row=j(q*4+r)
      f4 sc[4];
#pragma unroll
      for (int jt = 0; jt < 4; ++jt) {
        f4 c = {0.f, 0.f, 0.f, 0.f};
        c = __builtin_amdgcn_mfma_f32_16x16x32_bf16(kf[jt][0], qf[f][0], c, 0, 0, 0);
        c = __builtin_amdgcn_mfma_f32_16x16x32_bf16(kf[jt][1], qf[f][1], c, 0, 0, 0);
        sc[jt] = c;
      }
      float ls = 0.f;
#pragma unroll
      for (int jt = 0; jt < 4; ++jt)
#pragma unroll
        for (int r = 0; r < 4; ++r) {
          float p = __builtin_exp2f(sc[jt][r]);  // log2e pre-folded into Q
          sc[jt][r] = p;
          ls += p;
        }
      lsum[f] += ls;

      unsigned pk01[4], pk23[4];
#pragma unroll
      for (int jt = 0; jt < 4; ++jt) {
        pk01[jt] = pack2(sc[jt][0], sc[jt][1]);
        pk23[jt] = pack2(sc[jt][2], sc[jt][3]);
      }
      // PV: O^T += V^T . P^T  (P^T shuffled into B-operand layout)
#pragma unroll
      for (int ks2 = 0; ks2 < 2; ++ks2) {
        union { unsigned u[4]; short8 s; } bu;
#pragma unroll
        for (int r = 0; r < 4; ++r) {
          int src = (qh2 + (r >> 1)) * 16 + l15;
          unsigned pl = (r & 1) ? pk23[ks2 * 2] : pk01[ks2 * 2];
          unsigned ph = (r & 1) ? pk23[ks2 * 2 + 1] : pk01[ks2 * 2 + 1];
          unsigned lo = __shfl(pl, src);
          unsigned hi = __shfl(ph, src);
          bu.u[r] = hi_half ? hi : lo;
        }
#pragma unroll
        for (int dt = 0; dt < 4; ++dt)
          acc[f][dt] = __builtin_amdgcn_mfma_f32_16x16x32_bf16(vf[ks2][dt], bu.s,
                                                               acc[f][dt], 0, 0, 0);
      }
    }
  }

  // epilogue: reduce l-sums, *gw, store bf16 to obfT[l][c]
  float g = gwp[bt * H_ + h];
#pragma unroll
  for (int f = 0; f < 2; ++f) {
    float ls = lsum[f];
    ls += __shfl_xor(ls, 16);
    ls += __shfl_xor(ls, 32);
    float inv = g / ls;
    int iglob = iw + f * 16 + l15;
    ushort_t* ob = obfT + ((size_t)(bt * 512 + iglob)) * 512 + h * 64;
#pragma unroll
    for (int dt = 0; dt < 4; ++dt) {
      uint2 pk;
      pk.x = pack2(acc[f][dt][0] * inv, acc[f][dt][1] * inv);
      pk.y = pack2(acc[f][dt][2] * inv, acc[f][dt][3] * inv);
      *(uint2*)&ob[dt * 16 + q * 4] = pk;
    }
  }
}

extern "C" void kernel_launch(void* const* d_in, const int* in_sizes, int n_in,
                              void* d_out, int out_size, void* d_ws, size_t ws_size,
                              hipStream_t stream) {
  const float* e   = (const float*)d_in[0];
  const float* x   = (const float*)d_in[1];
  const float* Wq  = (const float*)d_in[2];
  const float* bq  = (const float*)d_in[3];
  const float* Wkv = (const float*)d_in[4];
  const float* bkv = (const float*)d_in[5];
  const float* Wm  = (const float*)d_in[6];
  const float* bm  = (const float*)d_in[7];
  const float* Wg1 = (const float*)d_in[8];
  const float* bg1 = (const float*)d_in[9];
  const float* Wg2 = (const float*)d_in[10];
  const float* bg2 = (const float*)d_in[11];
  float* out = (float*)d_out;

  float* ws = (float*)d_ws;
  float* pooled = ws;                  // 16384
  float* gwp    = ws + 16384;          // 256
  float* h1buf  = ws + 16640;          // 16384
  float* fb     = ws + 33024;
  ushort_t* ebfT = (ushort_t*)(fb);
  ushort_t* xbfT = (ushort_t*)(fb + 1 * 4194304);
  ushort_t* Qbf  = (ushort_t*)(fb + 2 * 4194304);
  ushort_t* Kbf  = (ushort_t*)(fb + 3 * 4194304);
  ushort_t* Vbf  = (ushort_t*)(fb + 4 * 4194304);
  ushort_t* obfT = (ushort_t*)(fb + 5 * 4194304);
  ushort_t* Wqb  = (ushort_t*)(fb + 6 * 4194304);
  ushort_t* Wkvb = Wqb + 262144;
  ushort_t* Wmb  = Wkvb + 524288;

  hipMemsetAsync(pooled, 0, 16384 * sizeof(float), stream);
  cvt3_kernel<<<dim3(512), dim3(256), 0, stream>>>(Wq, Wkv, Wm, Wqb, Wkvb, Wmb);
  tconv_kernel<<<dim3(8, 8, 64), dim3(256), 0, stream>>>(e, x, ebfT, xbfT, pooled);
  gate1_kernel<<<dim3(128, 32), dim3(256), 0, stream>>>(pooled, Wg1, bg1, h1buf);
  gate2_kernel<<<dim3(32), dim3(256), 0, stream>>>(h1buf, Wg2, bg2, gwp);
  // fused q + kv projections (normalize epilogues) -> Qbf, Kbf, Vbf
  gemm_mfma<<<dim3(4, 12, 32), dim3(256), 0, stream>>>(
      Wqb, ebfT, bq, Wkvb, xbfT, bkv, 3, nullptr, nullptr, Qbf, Kbf, Vbf, gwp);
  // attention -> obfT (LDS double-buffered, 4 query-blocks per (h,bt))
  attn_kernel<<<dim3(4, H_, 32), dim3(256), 0, stream>>>(Qbf, Kbf, Vbf, gwp, obfT);
  // output projection + bias + residual -> out
  gemm_mfma<<<dim3(4, 4, 32), dim3(256), 0, stream>>>(
      Wmb, obfT, bm, nullptr, nullptr, nullptr, 0, out, x, nullptr, nullptr,
      nullptr, gwp);
}